// Round 2
// baseline (1275.555 us; speedup 1.0000x reference)
//
#include <hip/hip_runtime.h>
#include <hip/hip_bf16.h>

#define NN   50000
#define NE   800000
#define NG   64
#define DH   128
#define DOUT 5000
#define BNEPS 1e-5f

// ---------- CSR build ----------
__global__ __launch_bounds__(256) void k_count(const int* __restrict__ dst, int* __restrict__ cnt) {
    int e = blockIdx.x * 256 + threadIdx.x;
    if (e < NE) atomicAdd(&cnt[dst[e]], 1);
}

__global__ __launch_bounds__(1024) void k_scan(int* __restrict__ cnt, int* __restrict__ rowptr,
                                               float* __restrict__ dis) {
    __shared__ int sums[1024];
    int t = threadIdx.x;
    const int CH = (NN + 1023) / 1024;
    int s = t * CH, e = min(s + CH, NN);
    int tot = 0;
    for (int j = s; j < e; j++) tot += cnt[j];
    sums[t] = tot;
    __syncthreads();
    for (int off = 1; off < 1024; off <<= 1) {
        int v = (t >= off) ? sums[t - off] : 0;
        __syncthreads();
        if (t >= off) sums[t] += v;
        __syncthreads();
    }
    int run = (t == 0) ? 0 : sums[t - 1];
    for (int j = s; j < e; j++) {
        rowptr[j] = run;
        int c = cnt[j];
        run += c;
        dis[j] = rsqrtf((float)(c + 1));   // deg includes self-loop
        cnt[j] = 0;                        // reuse as fill counter
    }
    if (t == 0) rowptr[NN] = NE;
}

__global__ __launch_bounds__(256) void k_fill(const int* __restrict__ ei, const int* __restrict__ rowptr,
                                              int* __restrict__ fil, const float* __restrict__ dis,
                                              int* __restrict__ col, float* __restrict__ wgt) {
    int e = blockIdx.x * 256 + threadIdx.x;
    if (e >= NE) return;
    int s = ei[e], d = ei[NE + e];
    int p = rowptr[d] + atomicAdd(&fil[d], 1);
    col[p] = s;
    wgt[p] = dis[s] * dis[d];
}

// ---------- GEMM: Y = X @ W  (N x 128 @ 128 x 128) ----------
__global__ __launch_bounds__(256) void k_gemm(const float* __restrict__ X, const float* __restrict__ W,
                                              float* __restrict__ Y) {
    int c = threadIdx.x & 127;
    int rg = threadIdx.x >> 7;
    int row0 = blockIdx.x * 32 + rg * 16;
    if (row0 >= NN) return;
    const float* Xb = X + row0 * DH;   // uniform per wave-group -> scalar loads
    float acc[16];
#pragma unroll
    for (int i = 0; i < 16; i++) acc[i] = 0.f;
    for (int k = 0; k < DH; k += 2) {
        float wv0 = W[k * DH + c];
        float wv1 = W[(k + 1) * DH + c];
#pragma unroll
        for (int i = 0; i < 16; i++) {
            acc[i] = fmaf(Xb[i * DH + k], wv0, acc[i]);
            acc[i] = fmaf(Xb[i * DH + k + 1], wv1, acc[i]);
        }
    }
#pragma unroll
    for (int i = 0; i < 16; i++) Y[(row0 + i) * DH + c] = acc[i];
}

// ---------- aggregation + bias + BN stats ----------
__global__ __launch_bounds__(256) void k_agg(const float* __restrict__ HW, const int* __restrict__ rowptr,
                                             const int* __restrict__ col, const float* __restrict__ wgt,
                                             const float* __restrict__ dis, const float* __restrict__ bias,
                                             float* __restrict__ OUT, float* __restrict__ ssum,
                                             float* __restrict__ ssq) {
    __shared__ float lsum[DH], lsq[DH];
    int t = threadIdx.x;
    if (t < DH) { lsum[t] = 0.f; lsq[t] = 0.f; }
    __syncthreads();
    int wid = t >> 6, lane = t & 63;
    const float2* HW2 = (const float2*)HW;
    float2* OUT2 = (float2*)OUT;
    float2 bv = ((const float2*)bias)[lane];
    float sx = 0.f, sy = 0.f, qx = 0.f, qy = 0.f;
    int stride = gridDim.x * 4;
    for (int i = blockIdx.x * 4 + wid; i < NN; i += stride) {
        float sd = dis[i];
        float2 h = HW2[i * 64 + lane];
        float ax = sd * sd * h.x, ay = sd * sd * h.y;
        int p = rowptr[i], p1 = rowptr[i + 1];
        for (; p + 4 <= p1; p += 4) {
            int c0 = col[p], c1 = col[p + 1], c2 = col[p + 2], c3 = col[p + 3];
            float w0 = wgt[p], w1 = wgt[p + 1], w2 = wgt[p + 2], w3 = wgt[p + 3];
            float2 h0 = HW2[c0 * 64 + lane];
            float2 h1 = HW2[c1 * 64 + lane];
            float2 h2 = HW2[c2 * 64 + lane];
            float2 h3 = HW2[c3 * 64 + lane];
            ax = fmaf(w0, h0.x, ax); ay = fmaf(w0, h0.y, ay);
            ax = fmaf(w1, h1.x, ax); ay = fmaf(w1, h1.y, ay);
            ax = fmaf(w2, h2.x, ax); ay = fmaf(w2, h2.y, ay);
            ax = fmaf(w3, h3.x, ax); ay = fmaf(w3, h3.y, ay);
        }
        for (; p < p1; p++) {
            int c = col[p];
            float wv = wgt[p];
            float2 hv = HW2[c * 64 + lane];
            ax = fmaf(wv, hv.x, ax); ay = fmaf(wv, hv.y, ay);
        }
        ax += bv.x; ay += bv.y;
        OUT2[i * 64 + lane] = make_float2(ax, ay);
        sx += ax; sy += ay; qx += ax * ax; qy += ay * ay;
    }
    atomicAdd(&lsum[lane * 2], sx);
    atomicAdd(&lsum[lane * 2 + 1], sy);
    atomicAdd(&lsq[lane * 2], qx);
    atomicAdd(&lsq[lane * 2 + 1], qy);
    __syncthreads();
    if (t < DH) { atomicAdd(&ssum[t], lsum[t]); atomicAdd(&ssq[t], lsq[t]); }
}

__global__ void k_bnfin(const float* __restrict__ ssum, const float* __restrict__ ssq,
                        const float* __restrict__ g, const float* __restrict__ be,
                        float* __restrict__ scale, float* __restrict__ shift) {
    int f = threadIdx.x;
    float m = ssum[f] * (1.f / NN);
    float v = ssq[f] * (1.f / NN) - m * m;
    float r = rsqrtf(v + BNEPS);
    float sc = r * g[f];
    scale[f] = sc;
    shift[f] = fmaf(-m, sc, be[f]);
}

__global__ __launch_bounds__(256) void k_bnrelu(float* __restrict__ A, const float* __restrict__ scale,
                                                const float* __restrict__ shift) {
    __shared__ float sc[DH], sh[DH];
    if (threadIdx.x < DH) { sc[threadIdx.x] = scale[threadIdx.x]; sh[threadIdx.x] = shift[threadIdx.x]; }
    __syncthreads();
    float4* A4 = (float4*)A;
    const int total = NN * (DH / 4);
    for (int i = blockIdx.x * 256 + threadIdx.x; i < total; i += gridDim.x * 256) {
        int f = (i & 31) * 4;
        float4 v = A4[i];
        v.x = fmaxf(fmaf(v.x, sc[f], sh[f]), 0.f);
        v.y = fmaxf(fmaf(v.y, sc[f + 1], sh[f + 1]), 0.f);
        v.z = fmaxf(fmaf(v.z, sc[f + 2], sh[f + 2]), 0.f);
        v.w = fmaxf(fmaf(v.w, sc[f + 3], sh[f + 3]), 0.f);
        A4[i] = v;
    }
}

// ---------- gate MLP: relu(h@gw1+gb1)@gw2+gb2 ----------
__global__ __launch_bounds__(256) void k_gate(const float* __restrict__ H, const float* __restrict__ gw1,
                                              const float* __restrict__ gb1, const float* __restrict__ gw2,
                                              const float* __restrict__ gb2, float* __restrict__ gate) {
    __shared__ float w1s[DH * 64];
    __shared__ float rowbuf[4][DH];
    int t = threadIdx.x;
    for (int i = t; i < DH * 64; i += 256) w1s[i] = gw1[i];
    __syncthreads();
    int wid = t >> 6, lane = t & 63;
    float b1v = gb1[lane], w2v = gw2[lane], b2v = gb2[0];
    int nw = gridDim.x * 4;
    int iters = (NN + nw - 1) / nw;
    const float2* H2 = (const float2*)H;
    for (int it = 0; it < iters; it++) {
        int i = blockIdx.x * 4 + wid + it * nw;
        bool act = i < NN;
        if (act) {
            float2 hv = H2[i * 64 + lane];
            rowbuf[wid][lane * 2] = hv.x;
            rowbuf[wid][lane * 2 + 1] = hv.y;
        }
        __syncthreads();
        float hid = 0.f;
#pragma unroll 8
        for (int k = 0; k < DH; k++) hid = fmaf(rowbuf[wid][k], w1s[k * 64 + lane], hid);
        hid = fmaxf(hid + b1v, 0.f);
        float v = hid * w2v;
        for (int off = 32; off > 0; off >>= 1) v += __shfl_down(v, off, 64);
        if (act && lane == 0) gate[i] = v + b2v;
        __syncthreads();
    }
}

// ---------- per-group softmax pooling ----------
__device__ __forceinline__ int lbound(const int* __restrict__ a, int v) {
    int lo = 0, hi = NN;
    while (lo < hi) {
        int mid = (lo + hi) >> 1;
        if (a[mid] < v) lo = mid + 1; else hi = mid;
    }
    return lo;
}

__global__ __launch_bounds__(256) void k_pool(const float* __restrict__ H, const float* __restrict__ gate,
                                              const int* __restrict__ batch, float* __restrict__ pooled) {
    __shared__ float red[256];
    __shared__ float mS, invS;
    int g = blockIdx.x, t = threadIdx.x;
    int s = lbound(batch, g), e = lbound(batch, g + 1);
    float m = -INFINITY;
    for (int i = s + t; i < e; i += 256) m = fmaxf(m, gate[i]);
    red[t] = m; __syncthreads();
    for (int off = 128; off > 0; off >>= 1) { if (t < off) red[t] = fmaxf(red[t], red[t + off]); __syncthreads(); }
    if (t == 0) mS = red[0];
    __syncthreads();
    m = mS;
    float se = 0.f;
    for (int i = s + t; i < e; i += 256) se += __expf(gate[i] - m);
    red[t] = se; __syncthreads();
    for (int off = 128; off > 0; off >>= 1) { if (t < off) red[t] += red[t + off]; __syncthreads(); }
    if (t == 0) invS = (e > s) ? 1.f / red[0] : 0.f;
    __syncthreads();
    float inv = invS;
    __syncthreads();
    int f = t & 127, half = t >> 7;
    float acc = 0.f;
    for (int i = s + half; i < e; i += 2) acc += __expf(gate[i] - m) * H[i * DH + f];
    red[t] = acc; __syncthreads();
    if (t < DH) pooled[g * DH + t] = (red[t] + red[t + DH]) * inv;
}

// ---------- classifier: pooled @ cw + cb -> fp32 out ----------
__global__ __launch_bounds__(256) void k_cls(const float* __restrict__ pooled, const float* __restrict__ cw,
                                             const float* __restrict__ cb, float* __restrict__ out) {
    __shared__ float pr[DH];
    int g = blockIdx.y;
    if (threadIdx.x < DH) pr[threadIdx.x] = pooled[g * DH + threadIdx.x];
    __syncthreads();
    int j = blockIdx.x * 256 + threadIdx.x;
    if (j >= DOUT) return;
    float acc = cb[j];
#pragma unroll 8
    for (int k = 0; k < DH; k++) acc = fmaf(pr[k], cw[k * DOUT + j], acc);
    out[g * DOUT + j] = acc;
}

extern "C" void kernel_launch(void* const* d_in, const int* in_sizes, int n_in,
                              void* d_out, int out_size, void* d_ws, size_t ws_size,
                              hipStream_t stream) {
    const float* x     = (const float*)d_in[0];
    const int*   ei    = (const int*)d_in[1];
    const int*   batch = (const int*)d_in[2];
    const float* w[4]  = {(const float*)d_in[3], (const float*)d_in[7], (const float*)d_in[11], (const float*)d_in[15]};
    const float* bb[4] = {(const float*)d_in[4], (const float*)d_in[8], (const float*)d_in[12], (const float*)d_in[16]};
    const float* gg[4] = {(const float*)d_in[5], (const float*)d_in[9], (const float*)d_in[13], (const float*)d_in[17]};
    const float* be[4] = {(const float*)d_in[6], (const float*)d_in[10], (const float*)d_in[14], (const float*)d_in[18]};
    const float* gw1 = (const float*)d_in[19];
    const float* gb1 = (const float*)d_in[20];
    const float* gw2 = (const float*)d_in[21];
    const float* gb2 = (const float*)d_in[22];
    const float* cw  = (const float*)d_in[23];
    const float* cb  = (const float*)d_in[24];

    char* base = (char*)d_ws;
    size_t off = 0;
    auto take = [&](size_t n) -> char* { char* r = base + off; off = (off + n + 255) & ~(size_t)255; return r; };
    float* bufA   = (float*)take((size_t)NN * DH * 4);
    float* bufB   = (float*)take((size_t)NN * DH * 4);
    int*   colv   = (int*)take((size_t)NE * 4);
    float* wgt    = (float*)take((size_t)NE * 4);
    int*   rowptr = (int*)take((size_t)(NN + 1) * 4);
    int*   cnt    = (int*)take((size_t)NN * 4);
    float* dis    = (float*)take((size_t)NN * 4);
    float* gate   = (float*)take((size_t)NN * 4);
    float* stats  = (float*)take(2 * DH * 4);
    float* ssum = stats, *ssq = stats + DH;
    float* scale  = (float*)take(DH * 4);
    float* shift  = (float*)take(DH * 4);
    float* pooled = (float*)take((size_t)NG * DH * 4);

    hipMemsetAsync(cnt, 0, NN * 4, stream);
    k_count<<<(NE + 255) / 256, 256, 0, stream>>>(ei + NE, cnt);
    k_scan<<<1, 1024, 0, stream>>>(cnt, rowptr, dis);
    k_fill<<<(NE + 255) / 256, 256, 0, stream>>>(ei, rowptr, cnt, dis, colv, wgt);

    const float* cur = x;
    for (int L = 0; L < 4; L++) {
        k_gemm<<<(NN + 31) / 32, 256, 0, stream>>>(cur, w[L], bufB);
        hipMemsetAsync(stats, 0, 2 * DH * 4, stream);
        k_agg<<<2048, 256, 0, stream>>>(bufB, rowptr, colv, wgt, dis, bb[L], bufA, ssum, ssq);
        k_bnfin<<<1, DH, 0, stream>>>(ssum, ssq, gg[L], be[L], scale, shift);
        k_bnrelu<<<2048, 256, 0, stream>>>(bufA, scale, shift);
        cur = bufA;
    }
    k_gate<<<1024, 256, 0, stream>>>(bufA, gw1, gb1, gw2, gb2, gate);
    k_pool<<<NG, 256, 0, stream>>>(bufA, gate, batch, pooled);
    k_cls<<<dim3((DOUT + 255) / 256, NG), 256, 0, stream>>>(pooled, cw, cb, (float*)d_out);
}

// Round 3
// 1150.713 us; speedup vs baseline: 1.1085x; 1.1085x over previous
//
#include <hip/hip_runtime.h>
#include <hip/hip_bf16.h>

#define NN   50000
#define NE   800000
#define NG   64
#define DH   128
#define DOUT 5000
#define BNEPS 1e-5f
#define NBLK 196   // ceil(NN/256)

// ---------- CSR build ----------
__global__ __launch_bounds__(256) void k_count(const int* __restrict__ dst, int* __restrict__ cnt) {
    int e = blockIdx.x * 256 + threadIdx.x;
    if (e < NE) atomicAdd(&cnt[dst[e]], 1);
}

// hierarchical exclusive scan: block-local scan + block sums
__global__ __launch_bounds__(256) void k_blkscan(const int* __restrict__ cnt, int* __restrict__ rowptr,
                                                 int* __restrict__ bsum) {
    __shared__ int s[256];
    int t = threadIdx.x, i = blockIdx.x * 256 + t;
    int v = (i < NN) ? cnt[i] : 0;
    s[t] = v;
    __syncthreads();
    for (int off = 1; off < 256; off <<= 1) {
        int x = (t >= off) ? s[t - off] : 0;
        __syncthreads();
        s[t] += x;
        __syncthreads();
    }
    if (i < NN) rowptr[i] = s[t] - v;          // exclusive within block
    if (t == 255) bsum[blockIdx.x] = s[255];   // block total
}

__global__ __launch_bounds__(256) void k_bscan(const int* __restrict__ bsum, int* __restrict__ boff) {
    __shared__ int s[256];
    int t = threadIdx.x;
    int v = (t < NBLK) ? bsum[t] : 0;
    s[t] = v;
    __syncthreads();
    for (int off = 1; off < 256; off <<= 1) {
        int x = (t >= off) ? s[t - off] : 0;
        __syncthreads();
        s[t] += x;
        __syncthreads();
    }
    if (t < NBLK) boff[t] = s[t] - v;          // exclusive across blocks
}

__global__ __launch_bounds__(256) void k_fin(int* __restrict__ rowptr, const int* __restrict__ boff,
                                             int* __restrict__ cnt, float* __restrict__ dis) {
    int i = blockIdx.x * 256 + threadIdx.x;
    if (i >= NN) { if (i == NN) rowptr[NN] = NE; return; }
    rowptr[i] += boff[blockIdx.x];
    dis[i] = rsqrtf((float)(cnt[i] + 1));      // deg includes self-loop
    cnt[i] = 0;                                // reuse as fill counter
}

__global__ __launch_bounds__(256) void k_fill(const int* __restrict__ ei, const int* __restrict__ rowptr,
                                              int* __restrict__ fil, const float* __restrict__ dis,
                                              int* __restrict__ col, float* __restrict__ wgt) {
    int e = blockIdx.x * 256 + threadIdx.x;
    if (e >= NE) return;
    int s = ei[e], d = ei[NE + e];
    int p = rowptr[d] + atomicAdd(&fil[d], 1);
    col[p] = s;
    wgt[p] = dis[s] * dis[d];
}

// ---------- GEMM: Y = X @ W  (N x 128 @ 128 x 128) ----------
__global__ __launch_bounds__(256) void k_gemm(const float* __restrict__ X, const float* __restrict__ W,
                                              float* __restrict__ Y) {
    int c = threadIdx.x & 127;
    int rg = threadIdx.x >> 7;
    int row0 = blockIdx.x * 32 + rg * 16;
    if (row0 >= NN) return;
    const float* Xb = X + row0 * DH;
    float acc[16];
#pragma unroll
    for (int i = 0; i < 16; i++) acc[i] = 0.f;
    for (int k = 0; k < DH; k += 2) {
        float wv0 = W[k * DH + c];
        float wv1 = W[(k + 1) * DH + c];
#pragma unroll
        for (int i = 0; i < 16; i++) {
            acc[i] = fmaf(Xb[i * DH + k], wv0, acc[i]);
            acc[i] = fmaf(Xb[i * DH + k + 1], wv1, acc[i]);
        }
    }
#pragma unroll
    for (int i = 0; i < 16; i++) Y[(row0 + i) * DH + c] = acc[i];
}

// ---------- aggregation + bias + BN stats ----------
__global__ __launch_bounds__(256) void k_agg(const float* __restrict__ HW, const int* __restrict__ rowptr,
                                             const int* __restrict__ col, const float* __restrict__ wgt,
                                             const float* __restrict__ dis, const float* __restrict__ bias,
                                             float* __restrict__ OUT, float* __restrict__ ssum,
                                             float* __restrict__ ssq) {
    __shared__ float lsum[DH], lsq[DH];
    int t = threadIdx.x;
    if (t < DH) { lsum[t] = 0.f; lsq[t] = 0.f; }
    __syncthreads();
    int wid = t >> 6, lane = t & 63;
    const float2* HW2 = (const float2*)HW;
    float2* OUT2 = (float2*)OUT;
    float2 bv = ((const float2*)bias)[lane];
    float sx = 0.f, sy = 0.f, qx = 0.f, qy = 0.f;
    int stride = gridDim.x * 4;
    for (int i = blockIdx.x * 4 + wid; i < NN; i += stride) {
        float sd = dis[i];
        float2 h = HW2[i * 64 + lane];
        float ax = sd * sd * h.x, ay = sd * sd * h.y;
        int p = rowptr[i], p1 = rowptr[i + 1];
        for (; p + 4 <= p1; p += 4) {
            int c0 = col[p], c1 = col[p + 1], c2 = col[p + 2], c3 = col[p + 3];
            float w0 = wgt[p], w1 = wgt[p + 1], w2 = wgt[p + 2], w3 = wgt[p + 3];
            float2 h0 = HW2[c0 * 64 + lane];
            float2 h1 = HW2[c1 * 64 + lane];
            float2 h2 = HW2[c2 * 64 + lane];
            float2 h3 = HW2[c3 * 64 + lane];
            ax = fmaf(w0, h0.x, ax); ay = fmaf(w0, h0.y, ay);
            ax = fmaf(w1, h1.x, ax); ay = fmaf(w1, h1.y, ay);
            ax = fmaf(w2, h2.x, ax); ay = fmaf(w2, h2.y, ay);
            ax = fmaf(w3, h3.x, ax); ay = fmaf(w3, h3.y, ay);
        }
        for (; p < p1; p++) {
            int c = col[p];
            float wv = wgt[p];
            float2 hv = HW2[c * 64 + lane];
            ax = fmaf(wv, hv.x, ax); ay = fmaf(wv, hv.y, ay);
        }
        ax += bv.x; ay += bv.y;
        OUT2[i * 64 + lane] = make_float2(ax, ay);
        sx += ax; sy += ay; qx += ax * ax; qy += ay * ay;
    }
    atomicAdd(&lsum[lane * 2], sx);
    atomicAdd(&lsum[lane * 2 + 1], sy);
    atomicAdd(&lsq[lane * 2], qx);
    atomicAdd(&lsq[lane * 2 + 1], qy);
    __syncthreads();
    if (t < DH) { atomicAdd(&ssum[t], lsum[t]); atomicAdd(&ssq[t], lsq[t]); }
}

__global__ void k_bnfin(const float* __restrict__ ssum, const float* __restrict__ ssq,
                        const float* __restrict__ g, const float* __restrict__ be,
                        float* __restrict__ scale, float* __restrict__ shift) {
    int f = threadIdx.x;
    float m = ssum[f] * (1.f / NN);
    float v = ssq[f] * (1.f / NN) - m * m;
    float r = rsqrtf(v + BNEPS);
    float sc = r * g[f];
    scale[f] = sc;
    shift[f] = fmaf(-m, sc, be[f]);
}

__global__ __launch_bounds__(256) void k_bnrelu(float* __restrict__ A, const float* __restrict__ scale,
                                                const float* __restrict__ shift) {
    __shared__ float sc[DH], sh[DH];
    if (threadIdx.x < DH) { sc[threadIdx.x] = scale[threadIdx.x]; sh[threadIdx.x] = shift[threadIdx.x]; }
    __syncthreads();
    float4* A4 = (float4*)A;
    const int total = NN * (DH / 4);
    for (int i = blockIdx.x * 256 + threadIdx.x; i < total; i += gridDim.x * 256) {
        int f = (i & 31) * 4;
        float4 v = A4[i];
        v.x = fmaxf(fmaf(v.x, sc[f], sh[f]), 0.f);
        v.y = fmaxf(fmaf(v.y, sc[f + 1], sh[f + 1]), 0.f);
        v.z = fmaxf(fmaf(v.z, sc[f + 2], sh[f + 2]), 0.f);
        v.w = fmaxf(fmaf(v.w, sc[f + 3], sh[f + 3]), 0.f);
        A4[i] = v;
    }
}

// ---------- gate MLP: relu(h@gw1+gb1)@gw2+gb2 ----------
__global__ __launch_bounds__(256) void k_gate(const float* __restrict__ H, const float* __restrict__ gw1,
                                              const float* __restrict__ gb1, const float* __restrict__ gw2,
                                              const float* __restrict__ gb2, float* __restrict__ gate) {
    __shared__ float w1s[DH * 64];
    __shared__ float rowbuf[4][DH];
    int t = threadIdx.x;
    for (int i = t; i < DH * 64; i += 256) w1s[i] = gw1[i];
    __syncthreads();
    int wid = t >> 6, lane = t & 63;
    float b1v = gb1[lane], w2v = gw2[lane], b2v = gb2[0];
    int nw = gridDim.x * 4;
    int iters = (NN + nw - 1) / nw;
    const float2* H2 = (const float2*)H;
    for (int it = 0; it < iters; it++) {
        int i = blockIdx.x * 4 + wid + it * nw;
        bool act = i < NN;
        if (act) {
            float2 hv = H2[i * 64 + lane];
            rowbuf[wid][lane * 2] = hv.x;
            rowbuf[wid][lane * 2 + 1] = hv.y;
        }
        __syncthreads();
        float hid = 0.f;
#pragma unroll 8
        for (int k = 0; k < DH; k++) hid = fmaf(rowbuf[wid][k], w1s[k * 64 + lane], hid);
        hid = fmaxf(hid + b1v, 0.f);
        float v = hid * w2v;
        for (int off = 32; off > 0; off >>= 1) v += __shfl_down(v, off, 64);
        if (act && lane == 0) gate[i] = v + b2v;
        __syncthreads();
    }
}

// ---------- per-group softmax pooling ----------
__device__ __forceinline__ int lbound(const int* __restrict__ a, int v) {
    int lo = 0, hi = NN;
    while (lo < hi) {
        int mid = (lo + hi) >> 1;
        if (a[mid] < v) lo = mid + 1; else hi = mid;
    }
    return lo;
}

__global__ __launch_bounds__(256) void k_pool(const float* __restrict__ H, const float* __restrict__ gate,
                                              const int* __restrict__ batch, float* __restrict__ pooled) {
    __shared__ float red[256];
    __shared__ float mS, invS;
    int g = blockIdx.x, t = threadIdx.x;
    int s = lbound(batch, g), e = lbound(batch, g + 1);
    float m = -INFINITY;
    for (int i = s + t; i < e; i += 256) m = fmaxf(m, gate[i]);
    red[t] = m; __syncthreads();
    for (int off = 128; off > 0; off >>= 1) { if (t < off) red[t] = fmaxf(red[t], red[t + off]); __syncthreads(); }
    if (t == 0) mS = red[0];
    __syncthreads();
    m = mS;
    float se = 0.f;
    for (int i = s + t; i < e; i += 256) se += __expf(gate[i] - m);
    red[t] = se; __syncthreads();
    for (int off = 128; off > 0; off >>= 1) { if (t < off) red[t] += red[t + off]; __syncthreads(); }
    if (t == 0) invS = (e > s) ? 1.f / red[0] : 0.f;
    __syncthreads();
    float inv = invS;
    __syncthreads();
    int f = t & 127, half = t >> 7;
    float acc = 0.f;
    for (int i = s + half; i < e; i += 2) acc += __expf(gate[i] - m) * H[i * DH + f];
    red[t] = acc; __syncthreads();
    if (t < DH) pooled[g * DH + t] = (red[t] + red[t + DH]) * inv;
}

// ---------- classifier: pooled @ cw + cb -> fp32 out ----------
__global__ __launch_bounds__(256) void k_cls(const float* __restrict__ pooled, const float* __restrict__ cw,
                                             const float* __restrict__ cb, float* __restrict__ out) {
    __shared__ float pr[DH];
    int g = blockIdx.y;
    if (threadIdx.x < DH) pr[threadIdx.x] = pooled[g * DH + threadIdx.x];
    __syncthreads();
    int j = blockIdx.x * 256 + threadIdx.x;
    if (j >= DOUT) return;
    float acc = cb[j];
#pragma unroll 8
    for (int k = 0; k < DH; k++) acc = fmaf(pr[k], cw[k * DOUT + j], acc);
    out[g * DOUT + j] = acc;
}

extern "C" void kernel_launch(void* const* d_in, const int* in_sizes, int n_in,
                              void* d_out, int out_size, void* d_ws, size_t ws_size,
                              hipStream_t stream) {
    const float* x     = (const float*)d_in[0];
    const int*   ei    = (const int*)d_in[1];
    const int*   batch = (const int*)d_in[2];
    const float* w[4]  = {(const float*)d_in[3], (const float*)d_in[7], (const float*)d_in[11], (const float*)d_in[15]};
    const float* bb[4] = {(const float*)d_in[4], (const float*)d_in[8], (const float*)d_in[12], (const float*)d_in[16]};
    const float* gg[4] = {(const float*)d_in[5], (const float*)d_in[9], (const float*)d_in[13], (const float*)d_in[17]};
    const float* be[4] = {(const float*)d_in[6], (const float*)d_in[10], (const float*)d_in[14], (const float*)d_in[18]};
    const float* gw1 = (const float*)d_in[19];
    const float* gb1 = (const float*)d_in[20];
    const float* gw2 = (const float*)d_in[21];
    const float* gb2 = (const float*)d_in[22];
    const float* cw  = (const float*)d_in[23];
    const float* cb  = (const float*)d_in[24];

    char* base = (char*)d_ws;
    size_t off = 0;
    auto take = [&](size_t n) -> char* { char* r = base + off; off = (off + n + 255) & ~(size_t)255; return r; };
    float* bufA   = (float*)take((size_t)NN * DH * 4);
    float* bufB   = (float*)take((size_t)NN * DH * 4);
    int*   colv   = (int*)take((size_t)NE * 4);
    float* wgt    = (float*)take((size_t)NE * 4);
    int*   rowptr = (int*)take((size_t)(NN + 1) * 4);
    int*   cnt    = (int*)take((size_t)NN * 4);
    float* dis    = (float*)take((size_t)NN * 4);
    float* gate   = (float*)take((size_t)NN * 4);
    float* stats  = (float*)take(2 * DH * 4);
    float* ssum = stats, *ssq = stats + DH;
    float* scale  = (float*)take(DH * 4);
    float* shift  = (float*)take(DH * 4);
    float* pooled = (float*)take((size_t)NG * DH * 4);
    int*   bsum   = (int*)take((size_t)256 * 4);
    int*   boff   = (int*)take((size_t)256 * 4);

    hipMemsetAsync(cnt, 0, NN * 4, stream);
    k_count<<<(NE + 255) / 256, 256, 0, stream>>>(ei + NE, cnt);
    k_blkscan<<<NBLK, 256, 0, stream>>>(cnt, rowptr, bsum);
    k_bscan<<<1, 256, 0, stream>>>(bsum, boff);
    k_fin<<<NBLK, 256, 0, stream>>>(rowptr, boff, cnt, dis);
    k_fill<<<(NE + 255) / 256, 256, 0, stream>>>(ei, rowptr, cnt, dis, colv, wgt);

    const float* cur = x;
    for (int L = 0; L < 4; L++) {
        k_gemm<<<(NN + 31) / 32, 256, 0, stream>>>(cur, w[L], bufB);
        hipMemsetAsync(stats, 0, 2 * DH * 4, stream);
        k_agg<<<2048, 256, 0, stream>>>(bufB, rowptr, colv, wgt, dis, bb[L], bufA, ssum, ssq);
        k_bnfin<<<1, DH, 0, stream>>>(ssum, ssq, gg[L], be[L], scale, shift);
        k_bnrelu<<<2048, 256, 0, stream>>>(bufA, scale, shift);
        cur = bufA;
    }
    k_gate<<<1024, 256, 0, stream>>>(bufA, gw1, gb1, gw2, gb2, gate);
    k_pool<<<NG, 256, 0, stream>>>(bufA, gate, batch, pooled);
    k_cls<<<dim3((DOUT + 255) / 256, NG), 256, 0, stream>>>(pooled, cw, cb, (float*)d_out);
}

// Round 4
// 1066.375 us; speedup vs baseline: 1.1962x; 1.0791x over previous
//
#include <hip/hip_runtime.h>
#include <hip/hip_bf16.h>

#define NN   50000
#define NE   800000
#define NG   64
#define DH   128
#define DOUT 5000
#define BNEPS 1e-5f
#define NBLK 196   // ceil(NN/256)

// ---------- CSR build ----------
__global__ __launch_bounds__(256) void k_count(const int* __restrict__ dst, int* __restrict__ cnt) {
    int e = blockIdx.x * 256 + threadIdx.x;
    if (e < NE) atomicAdd(&cnt[dst[e]], 1);
}

// hierarchical exclusive scan: block-local scan + block sums
__global__ __launch_bounds__(256) void k_blkscan(const int* __restrict__ cnt, int* __restrict__ rowptr,
                                                 int* __restrict__ bsum) {
    __shared__ int s[256];
    int t = threadIdx.x, i = blockIdx.x * 256 + t;
    int v = (i < NN) ? cnt[i] : 0;
    s[t] = v;
    __syncthreads();
    for (int off = 1; off < 256; off <<= 1) {
        int x = (t >= off) ? s[t - off] : 0;
        __syncthreads();
        s[t] += x;
        __syncthreads();
    }
    if (i < NN) rowptr[i] = s[t] - v;          // exclusive within block
    if (t == 255) bsum[blockIdx.x] = s[255];   // block total
}

__global__ __launch_bounds__(256) void k_bscan(const int* __restrict__ bsum, int* __restrict__ boff) {
    __shared__ int s[256];
    int t = threadIdx.x;
    int v = (t < NBLK) ? bsum[t] : 0;
    s[t] = v;
    __syncthreads();
    for (int off = 1; off < 256; off <<= 1) {
        int x = (t >= off) ? s[t - off] : 0;
        __syncthreads();
        s[t] += x;
        __syncthreads();
    }
    if (t < NBLK) boff[t] = s[t] - v;          // exclusive across blocks
}

__global__ __launch_bounds__(256) void k_fin(int* __restrict__ rowptr, const int* __restrict__ boff,
                                             int* __restrict__ cnt, float* __restrict__ dis) {
    int i = blockIdx.x * 256 + threadIdx.x;
    if (i >= NN) { if (i == NN) rowptr[NN] = NE; return; }
    rowptr[i] += boff[blockIdx.x];
    dis[i] = rsqrtf((float)(cnt[i] + 1));      // deg includes self-loop
    cnt[i] = 0;                                // reuse as fill counter
}

__global__ __launch_bounds__(256) void k_fill(const int* __restrict__ ei, const int* __restrict__ rowptr,
                                              int* __restrict__ fil, const float* __restrict__ dis,
                                              int* __restrict__ col, float* __restrict__ wgt) {
    int e = blockIdx.x * 256 + threadIdx.x;
    if (e >= NE) return;
    int s = ei[e], d = ei[NE + e];
    int p = rowptr[d] + atomicAdd(&fil[d], 1);
    col[p] = s;
    wgt[p] = dis[s] * dis[d];
}

// ---------- GEMM: Y = X @ W  (N x 128 @ 128 x 128) ----------
__global__ __launch_bounds__(256) void k_gemm(const float* __restrict__ X, const float* __restrict__ W,
                                              float* __restrict__ Y) {
    int c = threadIdx.x & 127;
    int rg = threadIdx.x >> 7;
    int row0 = blockIdx.x * 32 + rg * 16;
    if (row0 >= NN) return;
    const float* Xb = X + row0 * DH;
    float acc[16];
#pragma unroll
    for (int i = 0; i < 16; i++) acc[i] = 0.f;
    for (int k = 0; k < DH; k += 2) {
        float wv0 = W[k * DH + c];
        float wv1 = W[(k + 1) * DH + c];
#pragma unroll
        for (int i = 0; i < 16; i++) {
            acc[i] = fmaf(Xb[i * DH + k], wv0, acc[i]);
            acc[i] = fmaf(Xb[i * DH + k + 1], wv1, acc[i]);
        }
    }
#pragma unroll
    for (int i = 0; i < 16; i++) Y[(row0 + i) * DH + c] = acc[i];
}

// ---------- aggregation + bias + BN stats ----------
__global__ __launch_bounds__(256) void k_agg(const float* __restrict__ HW, const int* __restrict__ rowptr,
                                             const int* __restrict__ col, const float* __restrict__ wgt,
                                             const float* __restrict__ dis, const float* __restrict__ bias,
                                             float* __restrict__ OUT, float* __restrict__ ssum,
                                             float* __restrict__ ssq) {
    __shared__ float lsum[DH], lsq[DH];
    int t = threadIdx.x;
    if (t < DH) { lsum[t] = 0.f; lsq[t] = 0.f; }
    __syncthreads();
    int wid = t >> 6, lane = t & 63;
    const float2* HW2 = (const float2*)HW;
    float2* OUT2 = (float2*)OUT;
    float2 bv = ((const float2*)bias)[lane];
    float sx = 0.f, sy = 0.f, qx = 0.f, qy = 0.f;
    int stride = gridDim.x * 4;
    for (int i = blockIdx.x * 4 + wid; i < NN; i += stride) {
        float sd = dis[i];
        float2 h = HW2[i * 64 + lane];
        float ax = sd * sd * h.x, ay = sd * sd * h.y;
        int p = rowptr[i], p1 = rowptr[i + 1];
        for (; p + 4 <= p1; p += 4) {
            int c0 = col[p], c1 = col[p + 1], c2 = col[p + 2], c3 = col[p + 3];
            float w0 = wgt[p], w1 = wgt[p + 1], w2 = wgt[p + 2], w3 = wgt[p + 3];
            float2 h0 = HW2[c0 * 64 + lane];
            float2 h1 = HW2[c1 * 64 + lane];
            float2 h2 = HW2[c2 * 64 + lane];
            float2 h3 = HW2[c3 * 64 + lane];
            ax = fmaf(w0, h0.x, ax); ay = fmaf(w0, h0.y, ay);
            ax = fmaf(w1, h1.x, ax); ay = fmaf(w1, h1.y, ay);
            ax = fmaf(w2, h2.x, ax); ay = fmaf(w2, h2.y, ay);
            ax = fmaf(w3, h3.x, ax); ay = fmaf(w3, h3.y, ay);
        }
        for (; p < p1; p++) {
            int c = col[p];
            float wv = wgt[p];
            float2 hv = HW2[c * 64 + lane];
            ax = fmaf(wv, hv.x, ax); ay = fmaf(wv, hv.y, ay);
        }
        ax += bv.x; ay += bv.y;
        OUT2[i * 64 + lane] = make_float2(ax, ay);
        sx += ax; sy += ay; qx += ax * ax; qy += ay * ay;
    }
    atomicAdd(&lsum[lane * 2], sx);
    atomicAdd(&lsum[lane * 2 + 1], sy);
    atomicAdd(&lsq[lane * 2], qx);
    atomicAdd(&lsq[lane * 2 + 1], qy);
    __syncthreads();
    if (t < DH) { atomicAdd(&ssum[t], lsum[t]); atomicAdd(&ssq[t], lsq[t]); }
}

__global__ void k_bnfin(const float* __restrict__ ssum, const float* __restrict__ ssq,
                        const float* __restrict__ g, const float* __restrict__ be,
                        float* __restrict__ scale, float* __restrict__ shift) {
    int f = threadIdx.x;
    float m = ssum[f] * (1.f / NN);
    float v = ssq[f] * (1.f / NN) - m * m;
    float r = rsqrtf(v + BNEPS);
    float sc = r * g[f];
    scale[f] = sc;
    shift[f] = fmaf(-m, sc, be[f]);
}

__global__ __launch_bounds__(256) void k_bnrelu(float* __restrict__ A, const float* __restrict__ scale,
                                                const float* __restrict__ shift) {
    __shared__ float sc[DH], sh[DH];
    if (threadIdx.x < DH) { sc[threadIdx.x] = scale[threadIdx.x]; sh[threadIdx.x] = shift[threadIdx.x]; }
    __syncthreads();
    float4* A4 = (float4*)A;
    const int total = NN * (DH / 4);
    for (int i = blockIdx.x * 256 + threadIdx.x; i < total; i += gridDim.x * 256) {
        int f = (i & 31) * 4;
        float4 v = A4[i];
        v.x = fmaxf(fmaf(v.x, sc[f], sh[f]), 0.f);
        v.y = fmaxf(fmaf(v.y, sc[f + 1], sh[f + 1]), 0.f);
        v.z = fmaxf(fmaf(v.z, sc[f + 2], sh[f + 2]), 0.f);
        v.w = fmaxf(fmaf(v.w, sc[f + 3], sh[f + 3]), 0.f);
        A4[i] = v;
    }
}

// ---------- gate MLP: relu(h@gw1+gb1)@gw2+gb2 ----------
__global__ __launch_bounds__(256) void k_gate(const float* __restrict__ H, const float* __restrict__ gw1,
                                              const float* __restrict__ gb1, const float* __restrict__ gw2,
                                              const float* __restrict__ gb2, float* __restrict__ gate) {
    __shared__ float w1s[DH * 64];
    __shared__ float rowbuf[4][DH];
    int t = threadIdx.x;
    for (int i = t; i < DH * 64; i += 256) w1s[i] = gw1[i];
    __syncthreads();
    int wid = t >> 6, lane = t & 63;
    float b1v = gb1[lane], w2v = gw2[lane], b2v = gb2[0];
    int nw = gridDim.x * 4;
    int iters = (NN + nw - 1) / nw;
    const float2* H2 = (const float2*)H;
    for (int it = 0; it < iters; it++) {
        int i = blockIdx.x * 4 + wid + it * nw;
        bool act = i < NN;
        if (act) {
            float2 hv = H2[i * 64 + lane];
            rowbuf[wid][lane * 2] = hv.x;
            rowbuf[wid][lane * 2 + 1] = hv.y;
        }
        __syncthreads();
        float hid = 0.f;
#pragma unroll 8
        for (int k = 0; k < DH; k++) hid = fmaf(rowbuf[wid][k], w1s[k * 64 + lane], hid);
        hid = fmaxf(hid + b1v, 0.f);
        float v = hid * w2v;
        for (int off = 32; off > 0; off >>= 1) v += __shfl_down(v, off, 64);
        if (act && lane == 0) gate[i] = v + b2v;
        __syncthreads();
    }
}

// ---------- per-group softmax stats: m and 1/sum ----------
__device__ __forceinline__ int lbound(const int* __restrict__ a, int v) {
    int lo = 0, hi = NN;
    while (lo < hi) {
        int mid = (lo + hi) >> 1;
        if (a[mid] < v) lo = mid + 1; else hi = mid;
    }
    return lo;
}

__global__ __launch_bounds__(256) void k_pms(const float* __restrict__ gate, const int* __restrict__ batch,
                                             float* __restrict__ ms) {
    __shared__ float red[256];
    int g = blockIdx.x, t = threadIdx.x;
    int s = lbound(batch, g), e = lbound(batch, g + 1);
    float m = -INFINITY;
    for (int i = s + t; i < e; i += 256) m = fmaxf(m, gate[i]);
    red[t] = m; __syncthreads();
    for (int off = 128; off > 0; off >>= 1) { if (t < off) red[t] = fmaxf(red[t], red[t + off]); __syncthreads(); }
    m = red[0];
    __syncthreads();
    float se = 0.f;
    for (int i = s + t; i < e; i += 256) se += __expf(gate[i] - m);
    red[t] = se; __syncthreads();
    for (int off = 128; off > 0; off >>= 1) { if (t < off) red[t] += red[t + off]; __syncthreads(); }
    if (t == 0) {
        ms[g * 2] = m;
        ms[g * 2 + 1] = (e > s) ? 1.f / red[0] : 0.f;
    }
}

// ---------- node-parallel weighted pooling ----------
#define PNODES 8
__global__ __launch_bounds__(256) void k_pool2(const float* __restrict__ H, const float* __restrict__ gate,
                                               const int* __restrict__ batch, const float* __restrict__ ms,
                                               float* __restrict__ pooled) {
    int wid = threadIdx.x >> 6, lane = threadIdx.x & 63;
    int base = (blockIdx.x * 4 + wid) * PNODES;
    if (base >= NN) return;
    int end = min(base + PNODES, NN);
    const float2* H2 = (const float2*)H;
    float2 acc = make_float2(0.f, 0.f);
    int curg = batch[base];
    for (int i = base; i < end; i++) {
        int g = batch[i];
        if (g != curg) {
            atomicAdd(&pooled[curg * DH + lane * 2], acc.x);
            atomicAdd(&pooled[curg * DH + lane * 2 + 1], acc.y);
            acc = make_float2(0.f, 0.f);
            curg = g;
        }
        float a = __expf(gate[i] - ms[g * 2]) * ms[g * 2 + 1];
        float2 h = H2[i * 64 + lane];
        acc.x = fmaf(a, h.x, acc.x);
        acc.y = fmaf(a, h.y, acc.y);
    }
    atomicAdd(&pooled[curg * DH + lane * 2], acc.x);
    atomicAdd(&pooled[curg * DH + lane * 2 + 1], acc.y);
}

// ---------- classifier: pooled @ cw + cb -> fp32 out ----------
__global__ __launch_bounds__(256) void k_cls(const float* __restrict__ pooled, const float* __restrict__ cw,
                                             const float* __restrict__ cb, float* __restrict__ out) {
    __shared__ float pr[DH];
    int g = blockIdx.y;
    if (threadIdx.x < DH) pr[threadIdx.x] = pooled[g * DH + threadIdx.x];
    __syncthreads();
    int j = blockIdx.x * 256 + threadIdx.x;
    if (j >= DOUT) return;
    float acc = cb[j];
#pragma unroll 8
    for (int k = 0; k < DH; k++) acc = fmaf(pr[k], cw[k * DOUT + j], acc);
    out[g * DOUT + j] = acc;
}

extern "C" void kernel_launch(void* const* d_in, const int* in_sizes, int n_in,
                              void* d_out, int out_size, void* d_ws, size_t ws_size,
                              hipStream_t stream) {
    const float* x     = (const float*)d_in[0];
    const int*   ei    = (const int*)d_in[1];
    const int*   batch = (const int*)d_in[2];
    const float* w[4]  = {(const float*)d_in[3], (const float*)d_in[7], (const float*)d_in[11], (const float*)d_in[15]};
    const float* bb[4] = {(const float*)d_in[4], (const float*)d_in[8], (const float*)d_in[12], (const float*)d_in[16]};
    const float* gg[4] = {(const float*)d_in[5], (const float*)d_in[9], (const float*)d_in[13], (const float*)d_in[17]};
    const float* be[4] = {(const float*)d_in[6], (const float*)d_in[10], (const float*)d_in[14], (const float*)d_in[18]};
    const float* gw1 = (const float*)d_in[19];
    const float* gb1 = (const float*)d_in[20];
    const float* gw2 = (const float*)d_in[21];
    const float* gb2 = (const float*)d_in[22];
    const float* cw  = (const float*)d_in[23];
    const float* cb  = (const float*)d_in[24];

    char* base = (char*)d_ws;
    size_t off = 0;
    auto take = [&](size_t n) -> char* { char* r = base + off; off = (off + n + 255) & ~(size_t)255; return r; };
    float* bufA   = (float*)take((size_t)NN * DH * 4);
    float* bufB   = (float*)take((size_t)NN * DH * 4);
    int*   colv   = (int*)take((size_t)NE * 4);
    float* wgt    = (float*)take((size_t)NE * 4);
    int*   rowptr = (int*)take((size_t)(NN + 1) * 4);
    int*   cnt    = (int*)take((size_t)NN * 4);
    float* dis    = (float*)take((size_t)NN * 4);
    float* gate   = (float*)take((size_t)NN * 4);
    float* stats  = (float*)take(2 * DH * 4);
    float* ssum = stats, *ssq = stats + DH;
    float* scale  = (float*)take(DH * 4);
    float* shift  = (float*)take(DH * 4);
    float* pooled = (float*)take((size_t)NG * DH * 4);
    int*   bsum   = (int*)take((size_t)256 * 4);
    int*   boff   = (int*)take((size_t)256 * 4);
    float* ms     = (float*)take((size_t)NG * 2 * 4);

    hipMemsetAsync(cnt, 0, NN * 4, stream);
    k_count<<<(NE + 255) / 256, 256, 0, stream>>>(ei + NE, cnt);
    k_blkscan<<<NBLK, 256, 0, stream>>>(cnt, rowptr, bsum);
    k_bscan<<<1, 256, 0, stream>>>(bsum, boff);
    k_fin<<<NBLK, 256, 0, stream>>>(rowptr, boff, cnt, dis);
    k_fill<<<(NE + 255) / 256, 256, 0, stream>>>(ei, rowptr, cnt, dis, colv, wgt);

    const float* cur = x;
    for (int L = 0; L < 4; L++) {
        k_gemm<<<(NN + 31) / 32, 256, 0, stream>>>(cur, w[L], bufB);
        hipMemsetAsync(stats, 0, 2 * DH * 4, stream);
        k_agg<<<2048, 256, 0, stream>>>(bufB, rowptr, colv, wgt, dis, bb[L], bufA, ssum, ssq);
        k_bnfin<<<1, DH, 0, stream>>>(ssum, ssq, gg[L], be[L], scale, shift);
        k_bnrelu<<<2048, 256, 0, stream>>>(bufA, scale, shift);
        cur = bufA;
    }
    k_gate<<<1024, 256, 0, stream>>>(bufA, gw1, gb1, gw2, gb2, gate);
    k_pms<<<NG, 256, 0, stream>>>(gate, batch, ms);
    hipMemsetAsync(pooled, 0, (size_t)NG * DH * 4, stream);
    k_pool2<<<(NN + 4 * PNODES - 1) / (4 * PNODES), 256, 0, stream>>>(bufA, gate, batch, ms, pooled);
    k_cls<<<dim3((DOUT + 255) / 256, NG), 256, 0, stream>>>(pooled, cw, cb, (float*)d_out);
}

// Round 5
// 727.963 us; speedup vs baseline: 1.7522x; 1.4649x over previous
//
#include <hip/hip_runtime.h>
#include <hip/hip_bf16.h>

#define NN   50000
#define NE   800000
#define NG   64
#define DH   128
#define DOUT 5000
#define BNEPS 1e-5f
#define NBLK 196   // ceil(NN/256)
#define KB   32

// ---------- CSR build ----------
__global__ __launch_bounds__(256) void k_count(const int* __restrict__ dst, int* __restrict__ cnt) {
    int e = blockIdx.x * 256 + threadIdx.x;
    if (e < NE) atomicAdd(&cnt[dst[e]], 1);
}

__global__ __launch_bounds__(256) void k_blkscan(const int* __restrict__ cnt, int* __restrict__ rowptr,
                                                 int* __restrict__ bsum) {
    __shared__ int s[256];
    int t = threadIdx.x, i = blockIdx.x * 256 + t;
    int v = (i < NN) ? cnt[i] : 0;
    s[t] = v;
    __syncthreads();
    for (int off = 1; off < 256; off <<= 1) {
        int x = (t >= off) ? s[t - off] : 0;
        __syncthreads();
        s[t] += x;
        __syncthreads();
    }
    if (i < NN) rowptr[i] = s[t] - v;
    if (t == 255) bsum[blockIdx.x] = s[255];
}

__global__ __launch_bounds__(256) void k_bscan(const int* __restrict__ bsum, int* __restrict__ boff) {
    __shared__ int s[256];
    int t = threadIdx.x;
    int v = (t < NBLK) ? bsum[t] : 0;
    s[t] = v;
    __syncthreads();
    for (int off = 1; off < 256; off <<= 1) {
        int x = (t >= off) ? s[t - off] : 0;
        __syncthreads();
        s[t] += x;
        __syncthreads();
    }
    if (t < NBLK) boff[t] = s[t] - v;
}

__global__ __launch_bounds__(256) void k_fin(int* __restrict__ rowptr, const int* __restrict__ boff,
                                             int* __restrict__ cnt, float* __restrict__ dis) {
    int i = blockIdx.x * 256 + threadIdx.x;
    if (i >= NN) { if (i == NN) rowptr[NN] = NE; return; }
    rowptr[i] += boff[blockIdx.x];
    dis[i] = rsqrtf((float)(cnt[i] + 1));
    cnt[i] = 0;
}

__global__ __launch_bounds__(256) void k_fill(const int* __restrict__ ei, const int* __restrict__ rowptr,
                                              int* __restrict__ fil, const float* __restrict__ dis,
                                              int* __restrict__ col, float* __restrict__ wgt) {
    int e = blockIdx.x * 256 + threadIdx.x;
    if (e >= NE) return;
    int s = ei[e], d = ei[NE + e];
    int p = rowptr[d] + atomicAdd(&fil[d], 1);
    col[p] = s;
    wgt[p] = dis[s] * dis[d];
}

// ---------- tiled GEMM: Y = bnrelu?(X) @ W  (128-row x 128-col block, K tiled 32) ----------
__global__ __launch_bounds__(256) void k_gemm2(const float* __restrict__ X, const float* __restrict__ W,
                                               const float* __restrict__ scale, const float* __restrict__ shift,
                                               float* __restrict__ Y) {
    __shared__ float Xt[KB][DH + 1];   // transposed, padded: Xt[k][row]
    __shared__ float Ws[KB][DH];       // Ws[k][col]
    int t = threadIdx.x;
    int row0 = blockIdx.x * 128;
    int ra = (t >> 4) * 4;             // rows ra..ra+3, ra+64..ra+67
    int ca = (t & 15) * 4;             // cols ca..ca+3, ca+64..ca+67
    float acc[8][8];
#pragma unroll
    for (int i = 0; i < 8; i++)
#pragma unroll
        for (int j = 0; j < 8; j++) acc[i][j] = 0.f;

    for (int kt = 0; kt < DH / KB; kt++) {
        __syncthreads();
        // stage X^T (with fused BN+ReLU of previous layer)
#pragma unroll
        for (int i = 0; i < 4; i++) {
            int f = t + i * 256;           // [0,1024)
            int row = f >> 3;
            int kq = f & 7;
            int grow = min(row0 + row, NN - 1);
            float4 v = ((const float4*)X)[grow * (DH / 4) + kt * 8 + kq];
            if (scale) {
                float4 sc = ((const float4*)scale)[kt * 8 + kq];
                float4 sh = ((const float4*)shift)[kt * 8 + kq];
                v.x = fmaxf(fmaf(v.x, sc.x, sh.x), 0.f);
                v.y = fmaxf(fmaf(v.y, sc.y, sh.y), 0.f);
                v.z = fmaxf(fmaf(v.z, sc.z, sh.z), 0.f);
                v.w = fmaxf(fmaf(v.w, sc.w, sh.w), 0.f);
            }
            Xt[kq * 4 + 0][row] = v.x;
            Xt[kq * 4 + 1][row] = v.y;
            Xt[kq * 4 + 2][row] = v.z;
            Xt[kq * 4 + 3][row] = v.w;
        }
        // stage W rows kt*32..+31
#pragma unroll
        for (int i = 0; i < 4; i++) {
            int f = t + i * 256;
            int k = f >> 5;
            int cq = f & 31;
            float4 wv = ((const float4*)W)[(kt * KB + k) * (DH / 4) + cq];
            *(float4*)&Ws[k][cq * 4] = wv;
        }
        __syncthreads();
#pragma unroll 8
        for (int k = 0; k < KB; k++) {
            float ar[8], bc[8];
            ar[0] = Xt[k][ra + 0];  ar[1] = Xt[k][ra + 1];
            ar[2] = Xt[k][ra + 2];  ar[3] = Xt[k][ra + 3];
            ar[4] = Xt[k][ra + 64]; ar[5] = Xt[k][ra + 65];
            ar[6] = Xt[k][ra + 66]; ar[7] = Xt[k][ra + 67];
            float4 b0 = *(const float4*)&Ws[k][ca];
            float4 b1 = *(const float4*)&Ws[k][ca + 64];
            bc[0] = b0.x; bc[1] = b0.y; bc[2] = b0.z; bc[3] = b0.w;
            bc[4] = b1.x; bc[5] = b1.y; bc[6] = b1.z; bc[7] = b1.w;
#pragma unroll
            for (int ri = 0; ri < 8; ri++)
#pragma unroll
                for (int ci = 0; ci < 8; ci++)
                    acc[ri][ci] = fmaf(ar[ri], bc[ci], acc[ri][ci]);
        }
    }
    // epilogue: float4 stores
#pragma unroll
    for (int ri = 0; ri < 8; ri++) {
        int row = row0 + ((ri < 4) ? (ra + ri) : (ra + 60 + ri));
        if (row < NN) {
            float4 o0 = make_float4(acc[ri][0], acc[ri][1], acc[ri][2], acc[ri][3]);
            float4 o1 = make_float4(acc[ri][4], acc[ri][5], acc[ri][6], acc[ri][7]);
            ((float4*)Y)[row * (DH / 4) + (ca >> 2)] = o0;
            ((float4*)Y)[row * (DH / 4) + ((ca + 64) >> 2)] = o1;
        }
    }
}

// ---------- aggregation + bias + BN stats ----------
__global__ __launch_bounds__(256) void k_agg(const float* __restrict__ HW, const int* __restrict__ rowptr,
                                             const int* __restrict__ col, const float* __restrict__ wgt,
                                             const float* __restrict__ dis, const float* __restrict__ bias,
                                             float* __restrict__ OUT, float* __restrict__ ssum,
                                             float* __restrict__ ssq) {
    __shared__ float lsum[DH], lsq[DH];
    int t = threadIdx.x;
    if (t < DH) { lsum[t] = 0.f; lsq[t] = 0.f; }
    __syncthreads();
    int wid = t >> 6, lane = t & 63;
    const float2* HW2 = (const float2*)HW;
    float2* OUT2 = (float2*)OUT;
    float2 bv = ((const float2*)bias)[lane];
    float sx = 0.f, sy = 0.f, qx = 0.f, qy = 0.f;
    int stride = gridDim.x * 4;
    for (int i = blockIdx.x * 4 + wid; i < NN; i += stride) {
        float sd = dis[i];
        float2 h = HW2[i * 64 + lane];
        float ax = sd * sd * h.x, ay = sd * sd * h.y;
        int p = rowptr[i], p1 = rowptr[i + 1];
        for (; p + 4 <= p1; p += 4) {
            int c0 = col[p], c1 = col[p + 1], c2 = col[p + 2], c3 = col[p + 3];
            float w0 = wgt[p], w1 = wgt[p + 1], w2 = wgt[p + 2], w3 = wgt[p + 3];
            float2 h0 = HW2[c0 * 64 + lane];
            float2 h1 = HW2[c1 * 64 + lane];
            float2 h2 = HW2[c2 * 64 + lane];
            float2 h3 = HW2[c3 * 64 + lane];
            ax = fmaf(w0, h0.x, ax); ay = fmaf(w0, h0.y, ay);
            ax = fmaf(w1, h1.x, ax); ay = fmaf(w1, h1.y, ay);
            ax = fmaf(w2, h2.x, ax); ay = fmaf(w2, h2.y, ay);
            ax = fmaf(w3, h3.x, ax); ay = fmaf(w3, h3.y, ay);
        }
        for (; p < p1; p++) {
            int c = col[p];
            float wv = wgt[p];
            float2 hv = HW2[c * 64 + lane];
            ax = fmaf(wv, hv.x, ax); ay = fmaf(wv, hv.y, ay);
        }
        ax += bv.x; ay += bv.y;
        OUT2[i * 64 + lane] = make_float2(ax, ay);
        sx += ax; sy += ay; qx += ax * ax; qy += ay * ay;
    }
    atomicAdd(&lsum[lane * 2], sx);
    atomicAdd(&lsum[lane * 2 + 1], sy);
    atomicAdd(&lsq[lane * 2], qx);
    atomicAdd(&lsq[lane * 2 + 1], qy);
    __syncthreads();
    if (t < DH) { atomicAdd(&ssum[t], lsum[t]); atomicAdd(&ssq[t], lsq[t]); }
}

__global__ void k_bnfin(const float* __restrict__ ssum, const float* __restrict__ ssq,
                        const float* __restrict__ g, const float* __restrict__ be,
                        float* __restrict__ scale, float* __restrict__ shift) {
    int f = threadIdx.x;
    float m = ssum[f] * (1.f / NN);
    float v = ssq[f] * (1.f / NN) - m * m;
    float r = rsqrtf(v + BNEPS);
    float sc = r * g[f];
    scale[f] = sc;
    shift[f] = fmaf(-m, sc, be[f]);
}

__global__ __launch_bounds__(256) void k_bnrelu(float* __restrict__ A, const float* __restrict__ scale,
                                                const float* __restrict__ shift) {
    __shared__ float sc[DH], sh[DH];
    if (threadIdx.x < DH) { sc[threadIdx.x] = scale[threadIdx.x]; sh[threadIdx.x] = shift[threadIdx.x]; }
    __syncthreads();
    float4* A4 = (float4*)A;
    const int total = NN * (DH / 4);
    for (int i = blockIdx.x * 256 + threadIdx.x; i < total; i += gridDim.x * 256) {
        int f = (i & 31) * 4;
        float4 v = A4[i];
        v.x = fmaxf(fmaf(v.x, sc[f], sh[f]), 0.f);
        v.y = fmaxf(fmaf(v.y, sc[f + 1], sh[f + 1]), 0.f);
        v.z = fmaxf(fmaf(v.z, sc[f + 2], sh[f + 2]), 0.f);
        v.w = fmaxf(fmaf(v.w, sc[f + 3], sh[f + 3]), 0.f);
        A4[i] = v;
    }
}

// ---------- gate MLP ----------
__global__ __launch_bounds__(256) void k_gate(const float* __restrict__ H, const float* __restrict__ gw1,
                                              const float* __restrict__ gb1, const float* __restrict__ gw2,
                                              const float* __restrict__ gb2, float* __restrict__ gate) {
    __shared__ float w1s[DH * 64];
    __shared__ float rowbuf[4][DH];
    int t = threadIdx.x;
    for (int i = t; i < DH * 64; i += 256) w1s[i] = gw1[i];
    __syncthreads();
    int wid = t >> 6, lane = t & 63;
    float b1v = gb1[lane], w2v = gw2[lane], b2v = gb2[0];
    int nw = gridDim.x * 4;
    int iters = (NN + nw - 1) / nw;
    const float2* H2 = (const float2*)H;
    for (int it = 0; it < iters; it++) {
        int i = blockIdx.x * 4 + wid + it * nw;
        bool act = i < NN;
        if (act) {
            float2 hv = H2[i * 64 + lane];
            rowbuf[wid][lane * 2] = hv.x;
            rowbuf[wid][lane * 2 + 1] = hv.y;
        }
        __syncthreads();
        float hid = 0.f;
#pragma unroll 8
        for (int k = 0; k < DH; k++) hid = fmaf(rowbuf[wid][k], w1s[k * 64 + lane], hid);
        hid = fmaxf(hid + b1v, 0.f);
        float v = hid * w2v;
        for (int off = 32; off > 0; off >>= 1) v += __shfl_down(v, off, 64);
        if (act && lane == 0) gate[i] = v + b2v;
        __syncthreads();
    }
}

// ---------- per-group softmax stats ----------
__device__ __forceinline__ int lbound(const int* __restrict__ a, int v) {
    int lo = 0, hi = NN;
    while (lo < hi) {
        int mid = (lo + hi) >> 1;
        if (a[mid] < v) lo = mid + 1; else hi = mid;
    }
    return lo;
}

__global__ __launch_bounds__(256) void k_pms(const float* __restrict__ gate, const int* __restrict__ batch,
                                             float* __restrict__ ms) {
    __shared__ float red[256];
    int g = blockIdx.x, t = threadIdx.x;
    int s = lbound(batch, g), e = lbound(batch, g + 1);
    float m = -INFINITY;
    for (int i = s + t; i < e; i += 256) m = fmaxf(m, gate[i]);
    red[t] = m; __syncthreads();
    for (int off = 128; off > 0; off >>= 1) { if (t < off) red[t] = fmaxf(red[t], red[t + off]); __syncthreads(); }
    m = red[0];
    __syncthreads();
    float se = 0.f;
    for (int i = s + t; i < e; i += 256) se += __expf(gate[i] - m);
    red[t] = se; __syncthreads();
    for (int off = 128; off > 0; off >>= 1) { if (t < off) red[t] += red[t + off]; __syncthreads(); }
    if (t == 0) {
        ms[g * 2] = m;
        ms[g * 2 + 1] = (e > s) ? 1.f / red[0] : 0.f;
    }
}

// ---------- node-parallel weighted pooling ----------
#define PNODES 8
__global__ __launch_bounds__(256) void k_pool2(const float* __restrict__ H, const float* __restrict__ gate,
                                               const int* __restrict__ batch, const float* __restrict__ ms,
                                               float* __restrict__ pooled) {
    int wid = threadIdx.x >> 6, lane = threadIdx.x & 63;
    int base = (blockIdx.x * 4 + wid) * PNODES;
    if (base >= NN) return;
    int end = min(base + PNODES, NN);
    const float2* H2 = (const float2*)H;
    float2 acc = make_float2(0.f, 0.f);
    int curg = batch[base];
    for (int i = base; i < end; i++) {
        int g = batch[i];
        if (g != curg) {
            atomicAdd(&pooled[curg * DH + lane * 2], acc.x);
            atomicAdd(&pooled[curg * DH + lane * 2 + 1], acc.y);
            acc = make_float2(0.f, 0.f);
            curg = g;
        }
        float a = __expf(gate[i] - ms[g * 2]) * ms[g * 2 + 1];
        float2 h = H2[i * 64 + lane];
        acc.x = fmaf(a, h.x, acc.x);
        acc.y = fmaf(a, h.y, acc.y);
    }
    atomicAdd(&pooled[curg * DH + lane * 2], acc.x);
    atomicAdd(&pooled[curg * DH + lane * 2 + 1], acc.y);
}

// ---------- classifier ----------
__global__ __launch_bounds__(256) void k_cls(const float* __restrict__ pooled, const float* __restrict__ cw,
                                             const float* __restrict__ cb, float* __restrict__ out) {
    __shared__ float pr[DH];
    int g = blockIdx.y;
    if (threadIdx.x < DH) pr[threadIdx.x] = pooled[g * DH + threadIdx.x];
    __syncthreads();
    int j = blockIdx.x * 256 + threadIdx.x;
    if (j >= DOUT) return;
    float acc = cb[j];
#pragma unroll 8
    for (int k = 0; k < DH; k++) acc = fmaf(pr[k], cw[k * DOUT + j], acc);
    out[g * DOUT + j] = acc;
}

extern "C" void kernel_launch(void* const* d_in, const int* in_sizes, int n_in,
                              void* d_out, int out_size, void* d_ws, size_t ws_size,
                              hipStream_t stream) {
    const float* x     = (const float*)d_in[0];
    const int*   ei    = (const int*)d_in[1];
    const int*   batch = (const int*)d_in[2];
    const float* w[4]  = {(const float*)d_in[3], (const float*)d_in[7], (const float*)d_in[11], (const float*)d_in[15]};
    const float* bb[4] = {(const float*)d_in[4], (const float*)d_in[8], (const float*)d_in[12], (const float*)d_in[16]};
    const float* gg[4] = {(const float*)d_in[5], (const float*)d_in[9], (const float*)d_in[13], (const float*)d_in[17]};
    const float* be[4] = {(const float*)d_in[6], (const float*)d_in[10], (const float*)d_in[14], (const float*)d_in[18]};
    const float* gw1 = (const float*)d_in[19];
    const float* gb1 = (const float*)d_in[20];
    const float* gw2 = (const float*)d_in[21];
    const float* gb2 = (const float*)d_in[22];
    const float* cw  = (const float*)d_in[23];
    const float* cb  = (const float*)d_in[24];

    char* base = (char*)d_ws;
    size_t off = 0;
    auto take = [&](size_t n) -> char* { char* r = base + off; off = (off + n + 255) & ~(size_t)255; return r; };
    float* bufA   = (float*)take((size_t)NN * DH * 4);
    float* bufB   = (float*)take((size_t)NN * DH * 4);
    int*   colv   = (int*)take((size_t)NE * 4);
    float* wgt    = (float*)take((size_t)NE * 4);
    int*   rowptr = (int*)take((size_t)(NN + 1) * 4);
    int*   cnt    = (int*)take((size_t)NN * 4);
    float* dis    = (float*)take((size_t)NN * 4);
    float* gate   = (float*)take((size_t)NN * 4);
    float* stats  = (float*)take(2 * DH * 4);
    float* ssum = stats, *ssq = stats + DH;
    float* scale  = (float*)take(DH * 4);
    float* shift  = (float*)take(DH * 4);
    float* pooled = (float*)take((size_t)NG * DH * 4);
    int*   bsum   = (int*)take((size_t)256 * 4);
    int*   boff   = (int*)take((size_t)256 * 4);
    float* ms     = (float*)take((size_t)NG * 2 * 4);

    hipMemsetAsync(cnt, 0, NN * 4, stream);
    k_count<<<(NE + 255) / 256, 256, 0, stream>>>(ei + NE, cnt);
    k_blkscan<<<NBLK, 256, 0, stream>>>(cnt, rowptr, bsum);
    k_bscan<<<1, 256, 0, stream>>>(bsum, boff);
    k_fin<<<NBLK, 256, 0, stream>>>(rowptr, boff, cnt, dis);
    k_fill<<<(NE + 255) / 256, 256, 0, stream>>>(ei, rowptr, cnt, dis, colv, wgt);

    const int gemm_grid = (NN + 127) / 128;
    for (int L = 0; L < 4; L++) {
        k_gemm2<<<gemm_grid, 256, 0, stream>>>(L == 0 ? x : bufA, w[L],
                                               L == 0 ? nullptr : scale,
                                               L == 0 ? nullptr : shift, bufB);
        hipMemsetAsync(stats, 0, 2 * DH * 4, stream);
        k_agg<<<2048, 256, 0, stream>>>(bufB, rowptr, colv, wgt, dis, bb[L], bufA, ssum, ssq);
        k_bnfin<<<1, DH, 0, stream>>>(ssum, ssq, gg[L], be[L], scale, shift);
    }
    k_bnrelu<<<2048, 256, 0, stream>>>(bufA, scale, shift);   // layer-4 BN+ReLU materialized for gate/pool
    k_gate<<<1024, 256, 0, stream>>>(bufA, gw1, gb1, gw2, gb2, gate);
    k_pms<<<NG, 256, 0, stream>>>(gate, batch, ms);
    hipMemsetAsync(pooled, 0, (size_t)NG * DH * 4, stream);
    k_pool2<<<(NN + 4 * PNODES - 1) / (4 * PNODES), 256, 0, stream>>>(bufA, gate, batch, ms, pooled);
    k_cls<<<dim3((DOUT + 255) / 256, NG), 256, 0, stream>>>(pooled, cw, cb, (float*)d_out);
}

// Round 6
// 659.664 us; speedup vs baseline: 1.9336x; 1.1035x over previous
//
#include <hip/hip_runtime.h>
#include <hip/hip_bf16.h>
#include <hip/hip_fp16.h>

#define NN   50000
#define NE   800000
#define NG   64
#define DH   128
#define DOUT 5000
#define BNEPS 1e-5f
#define NBLK 196   // ceil(NN/256)
#define KB   32

// ---------- CSR build ----------
__global__ __launch_bounds__(256) void k_count(const int* __restrict__ dst, int* __restrict__ cnt) {
    int e = blockIdx.x * 256 + threadIdx.x;
    if (e < NE) atomicAdd(&cnt[dst[e]], 1);
}

__global__ __launch_bounds__(256) void k_blkscan(const int* __restrict__ cnt, int* __restrict__ rowptr,
                                                 int* __restrict__ bsum) {
    __shared__ int s[256];
    int t = threadIdx.x, i = blockIdx.x * 256 + t;
    int v = (i < NN) ? cnt[i] : 0;
    s[t] = v;
    __syncthreads();
    for (int off = 1; off < 256; off <<= 1) {
        int x = (t >= off) ? s[t - off] : 0;
        __syncthreads();
        s[t] += x;
        __syncthreads();
    }
    if (i < NN) rowptr[i] = s[t] - v;
    if (t == 255) bsum[blockIdx.x] = s[255];
}

__global__ __launch_bounds__(256) void k_bscan(const int* __restrict__ bsum, int* __restrict__ boff) {
    __shared__ int s[256];
    int t = threadIdx.x;
    int v = (t < NBLK) ? bsum[t] : 0;
    s[t] = v;
    __syncthreads();
    for (int off = 1; off < 256; off <<= 1) {
        int x = (t >= off) ? s[t - off] : 0;
        __syncthreads();
        s[t] += x;
        __syncthreads();
    }
    if (t < NBLK) boff[t] = s[t] - v;
}

__global__ __launch_bounds__(256) void k_fin(int* __restrict__ rowptr, const int* __restrict__ boff,
                                             int* __restrict__ cnt, float* __restrict__ dis) {
    int i = blockIdx.x * 256 + threadIdx.x;
    if (i >= NN) { if (i == NN) rowptr[NN] = NE; return; }
    rowptr[i] += boff[blockIdx.x];
    dis[i] = rsqrtf((float)(cnt[i] + 1));
    cnt[i] = 0;
}

__global__ __launch_bounds__(256) void k_fill(const int* __restrict__ ei, const int* __restrict__ rowptr,
                                              int* __restrict__ fil, const float* __restrict__ dis,
                                              int* __restrict__ col, float* __restrict__ wgt) {
    int e = blockIdx.x * 256 + threadIdx.x;
    if (e >= NE) return;
    int s = ei[e], d = ei[NE + e];
    int p = rowptr[d] + atomicAdd(&fil[d], 1);
    col[p] = s;
    wgt[p] = dis[s] * dis[d];
}

// ---------- tiled GEMM: Y(half) = bnrelu?(X) @ W ----------
__global__ __launch_bounds__(256) void k_gemm2(const float* __restrict__ X, const float* __restrict__ W,
                                               const float* __restrict__ scale, const float* __restrict__ shift,
                                               __half* __restrict__ Y) {
    __shared__ float Xt[KB][DH + 1];   // transposed, padded: Xt[k][row]
    __shared__ float Ws[KB][DH];       // Ws[k][col]
    int t = threadIdx.x;
    int row0 = blockIdx.x * 128;
    int ra = (t >> 4) * 4;
    int ca = (t & 15) * 4;
    float acc[8][8];
#pragma unroll
    for (int i = 0; i < 8; i++)
#pragma unroll
        for (int j = 0; j < 8; j++) acc[i][j] = 0.f;

    for (int kt = 0; kt < DH / KB; kt++) {
        __syncthreads();
#pragma unroll
        for (int i = 0; i < 4; i++) {
            int f = t + i * 256;
            int row = f >> 3;
            int kq = f & 7;
            int grow = min(row0 + row, NN - 1);
            float4 v = ((const float4*)X)[grow * (DH / 4) + kt * 8 + kq];
            if (scale) {
                float4 sc = ((const float4*)scale)[kt * 8 + kq];
                float4 sh = ((const float4*)shift)[kt * 8 + kq];
                v.x = fmaxf(fmaf(v.x, sc.x, sh.x), 0.f);
                v.y = fmaxf(fmaf(v.y, sc.y, sh.y), 0.f);
                v.z = fmaxf(fmaf(v.z, sc.z, sh.z), 0.f);
                v.w = fmaxf(fmaf(v.w, sc.w, sh.w), 0.f);
            }
            Xt[kq * 4 + 0][row] = v.x;
            Xt[kq * 4 + 1][row] = v.y;
            Xt[kq * 4 + 2][row] = v.z;
            Xt[kq * 4 + 3][row] = v.w;
        }
#pragma unroll
        for (int i = 0; i < 4; i++) {
            int f = t + i * 256;
            int k = f >> 5;
            int cq = f & 31;
            float4 wv = ((const float4*)W)[(kt * KB + k) * (DH / 4) + cq];
            *(float4*)&Ws[k][cq * 4] = wv;
        }
        __syncthreads();
#pragma unroll 8
        for (int k = 0; k < KB; k++) {
            float ar[8], bc[8];
            ar[0] = Xt[k][ra + 0];  ar[1] = Xt[k][ra + 1];
            ar[2] = Xt[k][ra + 2];  ar[3] = Xt[k][ra + 3];
            ar[4] = Xt[k][ra + 64]; ar[5] = Xt[k][ra + 65];
            ar[6] = Xt[k][ra + 66]; ar[7] = Xt[k][ra + 67];
            float4 b0 = *(const float4*)&Ws[k][ca];
            float4 b1 = *(const float4*)&Ws[k][ca + 64];
            bc[0] = b0.x; bc[1] = b0.y; bc[2] = b0.z; bc[3] = b0.w;
            bc[4] = b1.x; bc[5] = b1.y; bc[6] = b1.z; bc[7] = b1.w;
#pragma unroll
            for (int ri = 0; ri < 8; ri++)
#pragma unroll
                for (int ci = 0; ci < 8; ci++)
                    acc[ri][ci] = fmaf(ar[ri], bc[ci], acc[ri][ci]);
        }
    }
    // epilogue: half stores (8B per 4-col group)
#pragma unroll
    for (int ri = 0; ri < 8; ri++) {
        int row = row0 + ((ri < 4) ? (ra + ri) : (ra + 60 + ri));
        if (row < NN) {
            __half hv[8];
#pragma unroll
            for (int ci = 0; ci < 8; ci++) hv[ci] = __float2half(acc[ri][ci]);
            *(int2*)(Y + row * DH + ca) = *(int2*)hv;
            *(int2*)(Y + row * DH + ca + 64) = *(int2*)(hv + 4);
        }
    }
}

// ---------- aggregation (fp16 gather) + bias + BN stats ----------
__global__ __launch_bounds__(256) void k_agg(const __half* __restrict__ HW, const int* __restrict__ rowptr,
                                             const int* __restrict__ col, const float* __restrict__ wgt,
                                             const float* __restrict__ dis, const float* __restrict__ bias,
                                             float* __restrict__ OUT, float* __restrict__ ssum,
                                             float* __restrict__ ssq) {
    __shared__ float lsum[DH], lsq[DH];
    int t = threadIdx.x;
    if (t < DH) { lsum[t] = 0.f; lsq[t] = 0.f; }
    __syncthreads();
    int wid = t >> 6, lane = t & 63;
    const __half2* HW2 = (const __half2*)HW;
    float2* OUT2 = (float2*)OUT;
    float2 bv = ((const float2*)bias)[lane];
    float sx = 0.f, sy = 0.f, qx = 0.f, qy = 0.f;
    int stride = gridDim.x * 4;
    for (int i = blockIdx.x * 4 + wid; i < NN; i += stride) {
        float sd = dis[i];
        float2 h = __half22float2(HW2[i * 64 + lane]);
        float ax = sd * sd * h.x, ay = sd * sd * h.y;
        int p = rowptr[i], p1 = rowptr[i + 1];
        for (; p + 4 <= p1; p += 4) {
            int c0 = col[p], c1 = col[p + 1], c2 = col[p + 2], c3 = col[p + 3];
            float w0 = wgt[p], w1 = wgt[p + 1], w2 = wgt[p + 2], w3 = wgt[p + 3];
            float2 h0 = __half22float2(HW2[c0 * 64 + lane]);
            float2 h1 = __half22float2(HW2[c1 * 64 + lane]);
            float2 h2 = __half22float2(HW2[c2 * 64 + lane]);
            float2 h3 = __half22float2(HW2[c3 * 64 + lane]);
            ax = fmaf(w0, h0.x, ax); ay = fmaf(w0, h0.y, ay);
            ax = fmaf(w1, h1.x, ax); ay = fmaf(w1, h1.y, ay);
            ax = fmaf(w2, h2.x, ax); ay = fmaf(w2, h2.y, ay);
            ax = fmaf(w3, h3.x, ax); ay = fmaf(w3, h3.y, ay);
        }
        for (; p < p1; p++) {
            int c = col[p];
            float wv = wgt[p];
            float2 hv = __half22float2(HW2[c * 64 + lane]);
            ax = fmaf(wv, hv.x, ax); ay = fmaf(wv, hv.y, ay);
        }
        ax += bv.x; ay += bv.y;
        OUT2[i * 64 + lane] = make_float2(ax, ay);
        sx += ax; sy += ay; qx += ax * ax; qy += ay * ay;
    }
    atomicAdd(&lsum[lane * 2], sx);
    atomicAdd(&lsum[lane * 2 + 1], sy);
    atomicAdd(&lsq[lane * 2], qx);
    atomicAdd(&lsq[lane * 2 + 1], qy);
    __syncthreads();
    if (t < DH) { atomicAdd(&ssum[t], lsum[t]); atomicAdd(&ssq[t], lsq[t]); }
}

__global__ void k_bnfin(const float* __restrict__ ssum, const float* __restrict__ ssq,
                        const float* __restrict__ g, const float* __restrict__ be,
                        float* __restrict__ scale, float* __restrict__ shift) {
    int f = threadIdx.x;
    float m = ssum[f] * (1.f / NN);
    float v = ssq[f] * (1.f / NN) - m * m;
    float r = rsqrtf(v + BNEPS);
    float sc = r * g[f];
    scale[f] = sc;
    shift[f] = fmaf(-m, sc, be[f]);
}

__global__ __launch_bounds__(256) void k_bnrelu(float* __restrict__ A, const float* __restrict__ scale,
                                                const float* __restrict__ shift) {
    __shared__ float sc[DH], sh[DH];
    if (threadIdx.x < DH) { sc[threadIdx.x] = scale[threadIdx.x]; sh[threadIdx.x] = shift[threadIdx.x]; }
    __syncthreads();
    float4* A4 = (float4*)A;
    const int total = NN * (DH / 4);
    for (int i = blockIdx.x * 256 + threadIdx.x; i < total; i += gridDim.x * 256) {
        int f = (i & 31) * 4;
        float4 v = A4[i];
        v.x = fmaxf(fmaf(v.x, sc[f], sh[f]), 0.f);
        v.y = fmaxf(fmaf(v.y, sc[f + 1], sh[f + 1]), 0.f);
        v.z = fmaxf(fmaf(v.z, sc[f + 2], sh[f + 2]), 0.f);
        v.w = fmaxf(fmaf(v.w, sc[f + 3], sh[f + 3]), 0.f);
        A4[i] = v;
    }
}

// ---------- gate MLP ----------
__global__ __launch_bounds__(256) void k_gate(const float* __restrict__ H, const float* __restrict__ gw1,
                                              const float* __restrict__ gb1, const float* __restrict__ gw2,
                                              const float* __restrict__ gb2, float* __restrict__ gate) {
    __shared__ float w1s[DH * 64];
    __shared__ float rowbuf[4][DH];
    int t = threadIdx.x;
    for (int i = t; i < DH * 64; i += 256) w1s[i] = gw1[i];
    __syncthreads();
    int wid = t >> 6, lane = t & 63;
    float b1v = gb1[lane], w2v = gw2[lane], b2v = gb2[0];
    int nw = gridDim.x * 4;
    int iters = (NN + nw - 1) / nw;
    const float2* H2 = (const float2*)H;
    for (int it = 0; it < iters; it++) {
        int i = blockIdx.x * 4 + wid + it * nw;
        bool act = i < NN;
        if (act) {
            float2 hv = H2[i * 64 + lane];
            rowbuf[wid][lane * 2] = hv.x;
            rowbuf[wid][lane * 2 + 1] = hv.y;
        }
        __syncthreads();
        float hid = 0.f;
#pragma unroll 8
        for (int k = 0; k < DH; k++) hid = fmaf(rowbuf[wid][k], w1s[k * 64 + lane], hid);
        hid = fmaxf(hid + b1v, 0.f);
        float v = hid * w2v;
        for (int off = 32; off > 0; off >>= 1) v += __shfl_down(v, off, 64);
        if (act && lane == 0) gate[i] = v + b2v;
        __syncthreads();
    }
}

// ---------- per-group softmax stats ----------
__device__ __forceinline__ int lbound(const int* __restrict__ a, int v) {
    int lo = 0, hi = NN;
    while (lo < hi) {
        int mid = (lo + hi) >> 1;
        if (a[mid] < v) lo = mid + 1; else hi = mid;
    }
    return lo;
}

__global__ __launch_bounds__(256) void k_pms(const float* __restrict__ gate, const int* __restrict__ batch,
                                             float* __restrict__ ms) {
    __shared__ float red[256];
    int g = blockIdx.x, t = threadIdx.x;
    int s = lbound(batch, g), e = lbound(batch, g + 1);
    float m = -INFINITY;
    for (int i = s + t; i < e; i += 256) m = fmaxf(m, gate[i]);
    red[t] = m; __syncthreads();
    for (int off = 128; off > 0; off >>= 1) { if (t < off) red[t] = fmaxf(red[t], red[t + off]); __syncthreads(); }
    m = red[0];
    __syncthreads();
    float se = 0.f;
    for (int i = s + t; i < e; i += 256) se += __expf(gate[i] - m);
    red[t] = se; __syncthreads();
    for (int off = 128; off > 0; off >>= 1) { if (t < off) red[t] += red[t + off]; __syncthreads(); }
    if (t == 0) {
        ms[g * 2] = m;
        ms[g * 2 + 1] = (e > s) ? 1.f / red[0] : 0.f;
    }
}

// ---------- node-parallel weighted pooling ----------
#define PNODES 8
__global__ __launch_bounds__(256) void k_pool2(const float* __restrict__ H, const float* __restrict__ gate,
                                               const int* __restrict__ batch, const float* __restrict__ ms,
                                               float* __restrict__ pooled) {
    int wid = threadIdx.x >> 6, lane = threadIdx.x & 63;
    int base = (blockIdx.x * 4 + wid) * PNODES;
    if (base >= NN) return;
    int end = min(base + PNODES, NN);
    const float2* H2 = (const float2*)H;
    float2 acc = make_float2(0.f, 0.f);
    int curg = batch[base];
    for (int i = base; i < end; i++) {
        int g = batch[i];
        if (g != curg) {
            atomicAdd(&pooled[curg * DH + lane * 2], acc.x);
            atomicAdd(&pooled[curg * DH + lane * 2 + 1], acc.y);
            acc = make_float2(0.f, 0.f);
            curg = g;
        }
        float a = __expf(gate[i] - ms[g * 2]) * ms[g * 2 + 1];
        float2 h = H2[i * 64 + lane];
        acc.x = fmaf(a, h.x, acc.x);
        acc.y = fmaf(a, h.y, acc.y);
    }
    atomicAdd(&pooled[curg * DH + lane * 2], acc.x);
    atomicAdd(&pooled[curg * DH + lane * 2 + 1], acc.y);
}

// ---------- classifier ----------
__global__ __launch_bounds__(256) void k_cls(const float* __restrict__ pooled, const float* __restrict__ cw,
                                             const float* __restrict__ cb, float* __restrict__ out) {
    __shared__ float pr[DH];
    int g = blockIdx.y;
    if (threadIdx.x < DH) pr[threadIdx.x] = pooled[g * DH + threadIdx.x];
    __syncthreads();
    int j = blockIdx.x * 256 + threadIdx.x;
    if (j >= DOUT) return;
    float acc = cb[j];
#pragma unroll 8
    for (int k = 0; k < DH; k++) acc = fmaf(pr[k], cw[k * DOUT + j], acc);
    out[g * DOUT + j] = acc;
}

extern "C" void kernel_launch(void* const* d_in, const int* in_sizes, int n_in,
                              void* d_out, int out_size, void* d_ws, size_t ws_size,
                              hipStream_t stream) {
    const float* x     = (const float*)d_in[0];
    const int*   ei    = (const int*)d_in[1];
    const int*   batch = (const int*)d_in[2];
    const float* w[4]  = {(const float*)d_in[3], (const float*)d_in[7], (const float*)d_in[11], (const float*)d_in[15]};
    const float* bb[4] = {(const float*)d_in[4], (const float*)d_in[8], (const float*)d_in[12], (const float*)d_in[16]};
    const float* gg[4] = {(const float*)d_in[5], (const float*)d_in[9], (const float*)d_in[13], (const float*)d_in[17]};
    const float* be[4] = {(const float*)d_in[6], (const float*)d_in[10], (const float*)d_in[14], (const float*)d_in[18]};
    const float* gw1 = (const float*)d_in[19];
    const float* gb1 = (const float*)d_in[20];
    const float* gw2 = (const float*)d_in[21];
    const float* gb2 = (const float*)d_in[22];
    const float* cw  = (const float*)d_in[23];
    const float* cb  = (const float*)d_in[24];

    char* base = (char*)d_ws;
    size_t off = 0;
    auto take = [&](size_t n) -> char* { char* r = base + off; off = (off + n + 255) & ~(size_t)255; return r; };
    float*  bufA   = (float*)take((size_t)NN * DH * 4);
    __half* bufB   = (__half*)take((size_t)NN * DH * 2);
    int*   colv   = (int*)take((size_t)NE * 4);
    float* wgt    = (float*)take((size_t)NE * 4);
    int*   rowptr = (int*)take((size_t)(NN + 1) * 4);
    int*   cnt    = (int*)take((size_t)NN * 4);
    float* dis    = (float*)take((size_t)NN * 4);
    float* gate   = (float*)take((size_t)NN * 4);
    float* stats  = (float*)take(2 * DH * 4);
    float* ssum = stats, *ssq = stats + DH;
    float* scale  = (float*)take(DH * 4);
    float* shift  = (float*)take(DH * 4);
    float* pooled = (float*)take((size_t)NG * DH * 4);
    int*   bsum   = (int*)take((size_t)256 * 4);
    int*   boff   = (int*)take((size_t)256 * 4);
    float* ms     = (float*)take((size_t)NG * 2 * 4);

    hipMemsetAsync(cnt, 0, NN * 4, stream);
    k_count<<<(NE + 255) / 256, 256, 0, stream>>>(ei + NE, cnt);
    k_blkscan<<<NBLK, 256, 0, stream>>>(cnt, rowptr, bsum);
    k_bscan<<<1, 256, 0, stream>>>(bsum, boff);
    k_fin<<<NBLK, 256, 0, stream>>>(rowptr, boff, cnt, dis);
    k_fill<<<(NE + 255) / 256, 256, 0, stream>>>(ei, rowptr, cnt, dis, colv, wgt);

    const int gemm_grid = (NN + 127) / 128;
    for (int L = 0; L < 4; L++) {
        k_gemm2<<<gemm_grid, 256, 0, stream>>>(L == 0 ? x : bufA, w[L],
                                               L == 0 ? nullptr : scale,
                                               L == 0 ? nullptr : shift, bufB);
        hipMemsetAsync(stats, 0, 2 * DH * 4, stream);
        k_agg<<<2048, 256, 0, stream>>>(bufB, rowptr, colv, wgt, dis, bb[L], bufA, ssum, ssq);
        k_bnfin<<<1, DH, 0, stream>>>(ssum, ssq, gg[L], be[L], scale, shift);
    }
    k_bnrelu<<<2048, 256, 0, stream>>>(bufA, scale, shift);   // layer-4 BN+ReLU for gate/pool
    k_gate<<<1024, 256, 0, stream>>>(bufA, gw1, gb1, gw2, gb2, gate);
    k_pms<<<NG, 256, 0, stream>>>(gate, batch, ms);
    hipMemsetAsync(pooled, 0, (size_t)NG * DH * 4, stream);
    k_pool2<<<(NN + 4 * PNODES - 1) / (4 * PNODES), 256, 0, stream>>>(bufA, gate, batch, ms, pooled);
    k_cls<<<dim3((DOUT + 255) / 256, NG), 256, 0, stream>>>(pooled, cw, cb, (float*)d_out);
}

// Round 7
// 658.650 us; speedup vs baseline: 1.9366x; 1.0015x over previous
//
#include <hip/hip_runtime.h>
#include <hip/hip_bf16.h>
#include <hip/hip_fp16.h>

#define NN   50000
#define NE   800000
#define NG   64
#define DH   128
#define DOUT 5000
#define BNEPS 1e-5f
#define NBLK 196   // ceil(NN/256)
#define KB   32

// ---------- CSR build ----------
__global__ __launch_bounds__(256) void k_count(const int* __restrict__ dst, int* __restrict__ cnt) {
    int e = blockIdx.x * 256 + threadIdx.x;
    if (e < NE) atomicAdd(&cnt[dst[e]], 1);
}

__global__ __launch_bounds__(256) void k_blkscan(const int* __restrict__ cnt, int* __restrict__ rowptr,
                                                 int* __restrict__ bsum) {
    __shared__ int s[256];
    int t = threadIdx.x, i = blockIdx.x * 256 + t;
    int v = (i < NN) ? cnt[i] : 0;
    s[t] = v;
    __syncthreads();
    for (int off = 1; off < 256; off <<= 1) {
        int x = (t >= off) ? s[t - off] : 0;
        __syncthreads();
        s[t] += x;
        __syncthreads();
    }
    if (i < NN) rowptr[i] = s[t] - v;
    if (t == 255) bsum[blockIdx.x] = s[255];
}

__global__ __launch_bounds__(256) void k_bscan(const int* __restrict__ bsum, int* __restrict__ boff) {
    __shared__ int s[256];
    int t = threadIdx.x;
    int v = (t < NBLK) ? bsum[t] : 0;
    s[t] = v;
    __syncthreads();
    for (int off = 1; off < 256; off <<= 1) {
        int x = (t >= off) ? s[t - off] : 0;
        __syncthreads();
        s[t] += x;
        __syncthreads();
    }
    if (t < NBLK) boff[t] = s[t] - v;
}

__global__ __launch_bounds__(256) void k_fin(int* __restrict__ rowptr, const int* __restrict__ boff,
                                             int* __restrict__ cnt, float* __restrict__ dis) {
    int i = blockIdx.x * 256 + threadIdx.x;
    if (i >= NN) { if (i == NN) rowptr[NN] = NE; return; }
    rowptr[i] += boff[blockIdx.x];
    dis[i] = rsqrtf((float)(cnt[i] + 1));
    cnt[i] = 0;
}

__global__ __launch_bounds__(256) void k_fill(const int* __restrict__ ei, const int* __restrict__ rowptr,
                                              int* __restrict__ fil, const float* __restrict__ dis,
                                              int* __restrict__ col, float* __restrict__ wgt) {
    int e = blockIdx.x * 256 + threadIdx.x;
    if (e >= NE) return;
    int s = ei[e], d = ei[NE + e];
    int p = rowptr[d] + atomicAdd(&fil[d], 1);
    col[p] = s;
    wgt[p] = dis[s] * dis[d];
}

// ---------- tiled GEMM: Y(half) = bnrelu?(X) @ W ----------
__global__ __launch_bounds__(256) void k_gemm2(const float* __restrict__ X, const float* __restrict__ W,
                                               const float* __restrict__ scale, const float* __restrict__ shift,
                                               __half* __restrict__ Y) {
    __shared__ float Xt[KB][DH + 1];
    __shared__ float Ws[KB][DH];
    int t = threadIdx.x;
    int row0 = blockIdx.x * 128;
    int ra = (t >> 4) * 4;
    int ca = (t & 15) * 4;
    float acc[8][8];
#pragma unroll
    for (int i = 0; i < 8; i++)
#pragma unroll
        for (int j = 0; j < 8; j++) acc[i][j] = 0.f;

    for (int kt = 0; kt < DH / KB; kt++) {
        __syncthreads();
#pragma unroll
        for (int i = 0; i < 4; i++) {
            int f = t + i * 256;
            int row = f >> 3;
            int kq = f & 7;
            int grow = min(row0 + row, NN - 1);
            float4 v = ((const float4*)X)[grow * (DH / 4) + kt * 8 + kq];
            if (scale) {
                float4 sc = ((const float4*)scale)[kt * 8 + kq];
                float4 sh = ((const float4*)shift)[kt * 8 + kq];
                v.x = fmaxf(fmaf(v.x, sc.x, sh.x), 0.f);
                v.y = fmaxf(fmaf(v.y, sc.y, sh.y), 0.f);
                v.z = fmaxf(fmaf(v.z, sc.z, sh.z), 0.f);
                v.w = fmaxf(fmaf(v.w, sc.w, sh.w), 0.f);
            }
            Xt[kq * 4 + 0][row] = v.x;
            Xt[kq * 4 + 1][row] = v.y;
            Xt[kq * 4 + 2][row] = v.z;
            Xt[kq * 4 + 3][row] = v.w;
        }
#pragma unroll
        for (int i = 0; i < 4; i++) {
            int f = t + i * 256;
            int k = f >> 5;
            int cq = f & 31;
            float4 wv = ((const float4*)W)[(kt * KB + k) * (DH / 4) + cq];
            *(float4*)&Ws[k][cq * 4] = wv;
        }
        __syncthreads();
#pragma unroll 8
        for (int k = 0; k < KB; k++) {
            float ar[8], bc[8];
            ar[0] = Xt[k][ra + 0];  ar[1] = Xt[k][ra + 1];
            ar[2] = Xt[k][ra + 2];  ar[3] = Xt[k][ra + 3];
            ar[4] = Xt[k][ra + 64]; ar[5] = Xt[k][ra + 65];
            ar[6] = Xt[k][ra + 66]; ar[7] = Xt[k][ra + 67];
            float4 b0 = *(const float4*)&Ws[k][ca];
            float4 b1 = *(const float4*)&Ws[k][ca + 64];
            bc[0] = b0.x; bc[1] = b0.y; bc[2] = b0.z; bc[3] = b0.w;
            bc[4] = b1.x; bc[5] = b1.y; bc[6] = b1.z; bc[7] = b1.w;
#pragma unroll
            for (int ri = 0; ri < 8; ri++)
#pragma unroll
                for (int ci = 0; ci < 8; ci++)
                    acc[ri][ci] = fmaf(ar[ri], bc[ci], acc[ri][ci]);
        }
    }
#pragma unroll
    for (int ri = 0; ri < 8; ri++) {
        int row = row0 + ((ri < 4) ? (ra + ri) : (ra + 60 + ri));
        if (row < NN) {
            __half hv[8];
#pragma unroll
            for (int ci = 0; ci < 8; ci++) hv[ci] = __float2half(acc[ri][ci]);
            *(int2*)(Y + row * DH + ca) = *(int2*)hv;
            *(int2*)(Y + row * DH + ca + 64) = *(int2*)(hv + 4);
        }
    }
}

// ---------- aggregation: 2 nodes per wave, 8B/lane gathers ----------
__global__ __launch_bounds__(256) void k_agg(const __half* __restrict__ HW, const int* __restrict__ rowptr,
                                             const int* __restrict__ col, const float* __restrict__ wgt,
                                             const float* __restrict__ dis, const float* __restrict__ bias,
                                             float* __restrict__ OUT, float* __restrict__ ssum,
                                             float* __restrict__ ssq) {
    __shared__ float lsum[DH], lsq[DH];
    int t = threadIdx.x;
    if (t < DH) { lsum[t] = 0.f; lsq[t] = 0.f; }
    __syncthreads();
    int wid = t >> 6, lane = t & 63;
    int sub = lane >> 5, sl = lane & 31;            // half-wave, sub-lane
    const int2* HW4 = (const int2*)HW;              // 4 fp16 feats / 8B, row stride 32
    float4* OUT4 = (float4*)OUT;                    // row stride 32
    float4 bv = ((const float4*)bias)[sl];
    float s0 = 0, s1 = 0, s2 = 0, s3 = 0, q0 = 0, q1 = 0, q2 = 0, q3 = 0;
    int gw = blockIdx.x * 4 + wid;                  // [0, 8192)
    for (int i = gw * 2 + sub; i < NN; i += 16384) {
        float sd = dis[i];
        int2 hr = HW4[i * 32 + sl];
        float2 f0 = __half22float2(*(__half2*)&hr.x);
        float2 f1 = __half22float2(*(__half2*)&hr.y);
        float a0 = sd * sd * f0.x, a1 = sd * sd * f0.y;
        float a2 = sd * sd * f1.x, a3 = sd * sd * f1.y;
        int p = rowptr[i], p1 = rowptr[i + 1];
        for (; p + 4 <= p1; p += 4) {
            int c0 = col[p], c1 = col[p + 1], c2 = col[p + 2], c3 = col[p + 3];
            float w0 = wgt[p], w1 = wgt[p + 1], w2 = wgt[p + 2], w3 = wgt[p + 3];
            int2 r0 = HW4[c0 * 32 + sl];
            int2 r1 = HW4[c1 * 32 + sl];
            int2 r2 = HW4[c2 * 32 + sl];
            int2 r3 = HW4[c3 * 32 + sl];
            float2 g0 = __half22float2(*(__half2*)&r0.x), g1 = __half22float2(*(__half2*)&r0.y);
            a0 = fmaf(w0, g0.x, a0); a1 = fmaf(w0, g0.y, a1); a2 = fmaf(w0, g1.x, a2); a3 = fmaf(w0, g1.y, a3);
            g0 = __half22float2(*(__half2*)&r1.x); g1 = __half22float2(*(__half2*)&r1.y);
            a0 = fmaf(w1, g0.x, a0); a1 = fmaf(w1, g0.y, a1); a2 = fmaf(w1, g1.x, a2); a3 = fmaf(w1, g1.y, a3);
            g0 = __half22float2(*(__half2*)&r2.x); g1 = __half22float2(*(__half2*)&r2.y);
            a0 = fmaf(w2, g0.x, a0); a1 = fmaf(w2, g0.y, a1); a2 = fmaf(w2, g1.x, a2); a3 = fmaf(w2, g1.y, a3);
            g0 = __half22float2(*(__half2*)&r3.x); g1 = __half22float2(*(__half2*)&r3.y);
            a0 = fmaf(w3, g0.x, a0); a1 = fmaf(w3, g0.y, a1); a2 = fmaf(w3, g1.x, a2); a3 = fmaf(w3, g1.y, a3);
        }
        for (; p < p1; p++) {
            int c = col[p];
            float wv = wgt[p];
            int2 r = HW4[c * 32 + sl];
            float2 g0 = __half22float2(*(__half2*)&r.x), g1 = __half22float2(*(__half2*)&r.y);
            a0 = fmaf(wv, g0.x, a0); a1 = fmaf(wv, g0.y, a1);
            a2 = fmaf(wv, g1.x, a2); a3 = fmaf(wv, g1.y, a3);
        }
        a0 += bv.x; a1 += bv.y; a2 += bv.z; a3 += bv.w;
        OUT4[i * 32 + sl] = make_float4(a0, a1, a2, a3);
        s0 += a0; s1 += a1; s2 += a2; s3 += a3;
        q0 += a0 * a0; q1 += a1 * a1; q2 += a2 * a2; q3 += a3 * a3;
    }
    atomicAdd(&lsum[sl * 4 + 0], s0); atomicAdd(&lsum[sl * 4 + 1], s1);
    atomicAdd(&lsum[sl * 4 + 2], s2); atomicAdd(&lsum[sl * 4 + 3], s3);
    atomicAdd(&lsq[sl * 4 + 0], q0);  atomicAdd(&lsq[sl * 4 + 1], q1);
    atomicAdd(&lsq[sl * 4 + 2], q2);  atomicAdd(&lsq[sl * 4 + 3], q3);
    __syncthreads();
    if (t < DH) { atomicAdd(&ssum[t], lsum[t]); atomicAdd(&ssq[t], lsq[t]); }
}

__global__ void k_bnfin(const float* __restrict__ ssum, const float* __restrict__ ssq,
                        const float* __restrict__ g, const float* __restrict__ be,
                        float* __restrict__ scale, float* __restrict__ shift) {
    int f = threadIdx.x;
    float m = ssum[f] * (1.f / NN);
    float v = ssq[f] * (1.f / NN) - m * m;
    float r = rsqrtf(v + BNEPS);
    float sc = r * g[f];
    scale[f] = sc;
    shift[f] = fmaf(-m, sc, be[f]);
}

__global__ __launch_bounds__(256) void k_bnrelu(float* __restrict__ A, const float* __restrict__ scale,
                                                const float* __restrict__ shift) {
    __shared__ float sc[DH], sh[DH];
    if (threadIdx.x < DH) { sc[threadIdx.x] = scale[threadIdx.x]; sh[threadIdx.x] = shift[threadIdx.x]; }
    __syncthreads();
    float4* A4 = (float4*)A;
    const int total = NN * (DH / 4);
    for (int i = blockIdx.x * 256 + threadIdx.x; i < total; i += gridDim.x * 256) {
        int f = (i & 31) * 4;
        float4 v = A4[i];
        v.x = fmaxf(fmaf(v.x, sc[f], sh[f]), 0.f);
        v.y = fmaxf(fmaf(v.y, sc[f + 1], sh[f + 1]), 0.f);
        v.z = fmaxf(fmaf(v.z, sc[f + 2], sh[f + 2]), 0.f);
        v.w = fmaxf(fmaf(v.w, sc[f + 3], sh[f + 3]), 0.f);
        A4[i] = v;
    }
}

// ---------- gate MLP ----------
__global__ __launch_bounds__(256) void k_gate(const float* __restrict__ H, const float* __restrict__ gw1,
                                              const float* __restrict__ gb1, const float* __restrict__ gw2,
                                              const float* __restrict__ gb2, float* __restrict__ gate) {
    __shared__ float w1s[DH * 64];
    __shared__ float rowbuf[4][DH];
    int t = threadIdx.x;
    for (int i = t; i < DH * 64; i += 256) w1s[i] = gw1[i];
    __syncthreads();
    int wid = t >> 6, lane = t & 63;
    float b1v = gb1[lane], w2v = gw2[lane], b2v = gb2[0];
    int nw = gridDim.x * 4;
    int iters = (NN + nw - 1) / nw;
    const float2* H2 = (const float2*)H;
    for (int it = 0; it < iters; it++) {
        int i = blockIdx.x * 4 + wid + it * nw;
        bool act = i < NN;
        if (act) {
            float2 hv = H2[i * 64 + lane];
            rowbuf[wid][lane * 2] = hv.x;
            rowbuf[wid][lane * 2 + 1] = hv.y;
        }
        __syncthreads();
        float hid = 0.f;
#pragma unroll 8
        for (int k = 0; k < DH; k++) hid = fmaf(rowbuf[wid][k], w1s[k * 64 + lane], hid);
        hid = fmaxf(hid + b1v, 0.f);
        float v = hid * w2v;
        for (int off = 32; off > 0; off >>= 1) v += __shfl_down(v, off, 64);
        if (act && lane == 0) gate[i] = v + b2v;
        __syncthreads();
    }
}

// ---------- per-group softmax stats ----------
__device__ __forceinline__ int lbound(const int* __restrict__ a, int v) {
    int lo = 0, hi = NN;
    while (lo < hi) {
        int mid = (lo + hi) >> 1;
        if (a[mid] < v) lo = mid + 1; else hi = mid;
    }
    return lo;
}

__global__ __launch_bounds__(256) void k_pms(const float* __restrict__ gate, const int* __restrict__ batch,
                                             float* __restrict__ ms) {
    __shared__ float red[256];
    int g = blockIdx.x, t = threadIdx.x;
    int s = lbound(batch, g), e = lbound(batch, g + 1);
    float m = -INFINITY;
    for (int i = s + t; i < e; i += 256) m = fmaxf(m, gate[i]);
    red[t] = m; __syncthreads();
    for (int off = 128; off > 0; off >>= 1) { if (t < off) red[t] = fmaxf(red[t], red[t + off]); __syncthreads(); }
    m = red[0];
    __syncthreads();
    float se = 0.f;
    for (int i = s + t; i < e; i += 256) se += __expf(gate[i] - m);
    red[t] = se; __syncthreads();
    for (int off = 128; off > 0; off >>= 1) { if (t < off) red[t] += red[t + off]; __syncthreads(); }
    if (t == 0) {
        ms[g * 2] = m;
        ms[g * 2 + 1] = (e > s) ? 1.f / red[0] : 0.f;
    }
}

// ---------- node-parallel weighted pooling ----------
#define PNODES 8
__global__ __launch_bounds__(256) void k_pool2(const float* __restrict__ H, const float* __restrict__ gate,
                                               const int* __restrict__ batch, const float* __restrict__ ms,
                                               float* __restrict__ pooled) {
    int wid = threadIdx.x >> 6, lane = threadIdx.x & 63;
    int base = (blockIdx.x * 4 + wid) * PNODES;
    if (base >= NN) return;
    int end = min(base + PNODES, NN);
    const float2* H2 = (const float2*)H;
    float2 acc = make_float2(0.f, 0.f);
    int curg = batch[base];
    for (int i = base; i < end; i++) {
        int g = batch[i];
        if (g != curg) {
            atomicAdd(&pooled[curg * DH + lane * 2], acc.x);
            atomicAdd(&pooled[curg * DH + lane * 2 + 1], acc.y);
            acc = make_float2(0.f, 0.f);
            curg = g;
        }
        float a = __expf(gate[i] - ms[g * 2]) * ms[g * 2 + 1];
        float2 h = H2[i * 64 + lane];
        acc.x = fmaf(a, h.x, acc.x);
        acc.y = fmaf(a, h.y, acc.y);
    }
    atomicAdd(&pooled[curg * DH + lane * 2], acc.x);
    atomicAdd(&pooled[curg * DH + lane * 2 + 1], acc.y);
}

// ---------- classifier ----------
__global__ __launch_bounds__(256) void k_cls(const float* __restrict__ pooled, const float* __restrict__ cw,
                                             const float* __restrict__ cb, float* __restrict__ out) {
    __shared__ float pr[DH];
    int g = blockIdx.y;
    if (threadIdx.x < DH) pr[threadIdx.x] = pooled[g * DH + threadIdx.x];
    __syncthreads();
    int j = blockIdx.x * 256 + threadIdx.x;
    if (j >= DOUT) return;
    float acc = cb[j];
#pragma unroll 8
    for (int k = 0; k < DH; k++) acc = fmaf(pr[k], cw[k * DOUT + j], acc);
    out[g * DOUT + j] = acc;
}

extern "C" void kernel_launch(void* const* d_in, const int* in_sizes, int n_in,
                              void* d_out, int out_size, void* d_ws, size_t ws_size,
                              hipStream_t stream) {
    const float* x     = (const float*)d_in[0];
    const int*   ei    = (const int*)d_in[1];
    const int*   batch = (const int*)d_in[2];
    const float* w[4]  = {(const float*)d_in[3], (const float*)d_in[7], (const float*)d_in[11], (const float*)d_in[15]};
    const float* bb[4] = {(const float*)d_in[4], (const float*)d_in[8], (const float*)d_in[12], (const float*)d_in[16]};
    const float* gg[4] = {(const float*)d_in[5], (const float*)d_in[9], (const float*)d_in[13], (const float*)d_in[17]};
    const float* be[4] = {(const float*)d_in[6], (const float*)d_in[10], (const float*)d_in[14], (const float*)d_in[18]};
    const float* gw1 = (const float*)d_in[19];
    const float* gb1 = (const float*)d_in[20];
    const float* gw2 = (const float*)d_in[21];
    const float* gb2 = (const float*)d_in[22];
    const float* cw  = (const float*)d_in[23];
    const float* cb  = (const float*)d_in[24];

    char* base = (char*)d_ws;
    size_t off = 0;
    auto take = [&](size_t n) -> char* { char* r = base + off; off = (off + n + 255) & ~(size_t)255; return r; };
    float*  bufA   = (float*)take((size_t)NN * DH * 4);
    __half* bufB   = (__half*)take((size_t)NN * DH * 2);
    int*   colv   = (int*)take((size_t)NE * 4);
    float* wgt    = (float*)take((size_t)NE * 4);
    int*   rowptr = (int*)take((size_t)(NN + 1) * 4);
    int*   cnt    = (int*)take((size_t)NN * 4);
    float* dis    = (float*)take((size_t)NN * 4);
    float* gate   = (float*)take((size_t)NN * 4);
    float* stats  = (float*)take(2 * DH * 4);
    float* ssum = stats, *ssq = stats + DH;
    float* scale  = (float*)take(DH * 4);
    float* shift  = (float*)take(DH * 4);
    float* pooled = (float*)take((size_t)NG * DH * 4);
    int*   bsum   = (int*)take((size_t)256 * 4);
    int*   boff   = (int*)take((size_t)256 * 4);
    float* ms     = (float*)take((size_t)NG * 2 * 4);

    hipMemsetAsync(cnt, 0, NN * 4, stream);
    k_count<<<(NE + 255) / 256, 256, 0, stream>>>(ei + NE, cnt);
    k_blkscan<<<NBLK, 256, 0, stream>>>(cnt, rowptr, bsum);
    k_bscan<<<1, 256, 0, stream>>>(bsum, boff);
    k_fin<<<NBLK, 256, 0, stream>>>(rowptr, boff, cnt, dis);
    k_fill<<<(NE + 255) / 256, 256, 0, stream>>>(ei, rowptr, cnt, dis, colv, wgt);

    const int gemm_grid = (NN + 127) / 128;
    for (int L = 0; L < 4; L++) {
        k_gemm2<<<gemm_grid, 256, 0, stream>>>(L == 0 ? x : bufA, w[L],
                                               L == 0 ? nullptr : scale,
                                               L == 0 ? nullptr : shift, bufB);
        hipMemsetAsync(stats, 0, 2 * DH * 4, stream);
        k_agg<<<2048, 256, 0, stream>>>(bufB, rowptr, colv, wgt, dis, bb[L], bufA, ssum, ssq);
        k_bnfin<<<1, DH, 0, stream>>>(ssum, ssq, gg[L], be[L], scale, shift);
    }
    k_bnrelu<<<2048, 256, 0, stream>>>(bufA, scale, shift);   // layer-4 BN+ReLU for gate/pool
    k_gate<<<1024, 256, 0, stream>>>(bufA, gw1, gb1, gw2, gb2, gate);
    k_pms<<<NG, 256, 0, stream>>>(gate, batch, ms);
    hipMemsetAsync(pooled, 0, (size_t)NG * DH * 4, stream);
    k_pool2<<<(NN + 4 * PNODES - 1) / (4 * PNODES), 256, 0, stream>>>(bufA, gate, batch, ms, pooled);
    k_cls<<<dim3((DOUT + 255) / 256, NG), 256, 0, stream>>>(pooled, cw, cb, (float*)d_out);
}

// Round 8
// 604.937 us; speedup vs baseline: 2.1086x; 1.0888x over previous
//
#include <hip/hip_runtime.h>
#include <hip/hip_bf16.h>
#include <hip/hip_fp16.h>

#define NN   50000
#define NE   800000
#define NG   64
#define DH   128
#define DOUT 5000
#define BNEPS 1e-5f
#define NBLK 196   // ceil(NN/256)

typedef _Float16 h8 __attribute__((ext_vector_type(8)));
typedef float    f4 __attribute__((ext_vector_type(4)));

// ---------- CSR build ----------
__global__ __launch_bounds__(256) void k_count(const int* __restrict__ dst, int* __restrict__ cnt) {
    int e = blockIdx.x * 256 + threadIdx.x;
    if (e < NE) atomicAdd(&cnt[dst[e]], 1);
}

__global__ __launch_bounds__(256) void k_blkscan(const int* __restrict__ cnt, int* __restrict__ rowptr,
                                                 int* __restrict__ bsum) {
    __shared__ int s[256];
    int t = threadIdx.x, i = blockIdx.x * 256 + t;
    int v = (i < NN) ? cnt[i] : 0;
    s[t] = v;
    __syncthreads();
    for (int off = 1; off < 256; off <<= 1) {
        int x = (t >= off) ? s[t - off] : 0;
        __syncthreads();
        s[t] += x;
        __syncthreads();
    }
    if (i < NN) rowptr[i] = s[t] - v;
    if (t == 255) bsum[blockIdx.x] = s[255];
}

__global__ __launch_bounds__(256) void k_bscan(const int* __restrict__ bsum, int* __restrict__ boff) {
    __shared__ int s[256];
    int t = threadIdx.x;
    int v = (t < NBLK) ? bsum[t] : 0;
    s[t] = v;
    __syncthreads();
    for (int off = 1; off < 256; off <<= 1) {
        int x = (t >= off) ? s[t - off] : 0;
        __syncthreads();
        s[t] += x;
        __syncthreads();
    }
    if (t < NBLK) boff[t] = s[t] - v;
}

__global__ __launch_bounds__(256) void k_fin(int* __restrict__ rowptr, const int* __restrict__ boff,
                                             int* __restrict__ cnt, float* __restrict__ dis) {
    int i = blockIdx.x * 256 + threadIdx.x;
    if (i >= NN) { if (i == NN) rowptr[NN] = NE; return; }
    rowptr[i] += boff[blockIdx.x];
    dis[i] = rsqrtf((float)(cnt[i] + 1));
    cnt[i] = 0;
}

__global__ __launch_bounds__(256) void k_fill(const int* __restrict__ ei, const int* __restrict__ rowptr,
                                              int* __restrict__ fil, const float* __restrict__ dis,
                                              int* __restrict__ col, float* __restrict__ wgt) {
    int e = blockIdx.x * 256 + threadIdx.x;
    if (e >= NE) return;
    int s = ei[e], d = ei[NE + e];
    int p = rowptr[d] + atomicAdd(&fil[d], 1);
    col[p] = s;
    wgt[p] = dis[s] * dis[d];
}

// ---------- weight prep: Wt[c][k] = (half)W[k][c] for 4 layers ----------
__global__ __launch_bounds__(256) void k_wprep(const float* __restrict__ W0, const float* __restrict__ W1,
                                               const float* __restrict__ W2, const float* __restrict__ W3,
                                               __half* __restrict__ Wt) {
    const float* Ws[4] = {W0, W1, W2, W3};
    int m = blockIdx.x >> 4;            // matrix
    int chunk = blockIdx.x & 15;        // 1024 elems each
    const float* W = Ws[m];
    __half* O = Wt + m * DH * DH;
    int o = chunk * 1024 + threadIdx.x; // 4 strided elems
    for (int r = 0; r < 4; r++, o += 256) {
        int c = o >> 7, k = o & 127;
        O[o] = __float2half(W[k * DH + c]);
    }
}

// ---------- MFMA GEMM: Y(half) = bnrelu?(X) @ W  (64x128 block, 2x2 waves of 32x64) ----------
__global__ __launch_bounds__(256) void k_gemm3(const float* __restrict__ X, const __half* __restrict__ Wt,
                                               const float* __restrict__ scale, const float* __restrict__ shift,
                                               __half* __restrict__ Y) {
    int t = threadIdx.x;
    int lane = t & 63, wid = t >> 6;
    int wr = wid >> 1, wc = wid & 1;
    int row0 = blockIdx.x * 64;
    int lr = lane & 15, lk = (lane >> 4) * 8;   // fragment row/col low, k-octet

    f4 acc[2][4];
#pragma unroll
    for (int i = 0; i < 2; i++)
#pragma unroll
        for (int j = 0; j < 4; j++) acc[i][j] = (f4){0.f, 0.f, 0.f, 0.f};

    for (int kt = 0; kt < 4; kt++) {
        int kbase = kt * 32 + lk;
        // A fragments (2): rows row0 + wr*32 + fr*16 + lr, k = kbase..+7
        h8 afr[2];
#pragma unroll
        for (int fr = 0; fr < 2; fr++) {
            int gr = row0 + wr * 32 + fr * 16 + lr;
            gr = min(gr, NN - 1);
            const float4* p = (const float4*)(X + (size_t)gr * DH + kbase);
            float4 v0 = p[0], v1 = p[1];
            if (scale) {
                const float4* sc4 = (const float4*)(scale + kbase);
                const float4* sh4 = (const float4*)(shift + kbase);
                float4 s0 = sc4[0], s1 = sc4[1], h0 = sh4[0], h1 = sh4[1];
                v0.x = fmaxf(fmaf(v0.x, s0.x, h0.x), 0.f);
                v0.y = fmaxf(fmaf(v0.y, s0.y, h0.y), 0.f);
                v0.z = fmaxf(fmaf(v0.z, s0.z, h0.z), 0.f);
                v0.w = fmaxf(fmaf(v0.w, s0.w, h0.w), 0.f);
                v1.x = fmaxf(fmaf(v1.x, s1.x, h1.x), 0.f);
                v1.y = fmaxf(fmaf(v1.y, s1.y, h1.y), 0.f);
                v1.z = fmaxf(fmaf(v1.z, s1.z, h1.z), 0.f);
                v1.w = fmaxf(fmaf(v1.w, s1.w, h1.w), 0.f);
            }
            h8 a;
            a[0] = (_Float16)v0.x; a[1] = (_Float16)v0.y; a[2] = (_Float16)v0.z; a[3] = (_Float16)v0.w;
            a[4] = (_Float16)v1.x; a[5] = (_Float16)v1.y; a[6] = (_Float16)v1.z; a[7] = (_Float16)v1.w;
            afr[fr] = a;
        }
        // B fragments (4): col = wc*64 + fc*16 + lr, k = kbase..+7  (Wt row-major [col][k])
#pragma unroll
        for (int fc = 0; fc < 4; fc++) {
            int gc = wc * 64 + fc * 16 + lr;
            h8 b = *(const h8*)(Wt + (size_t)gc * DH + kbase);
#pragma unroll
            for (int fr = 0; fr < 2; fr++)
                acc[fr][fc] = __builtin_amdgcn_mfma_f32_16x16x32_f16(afr[fr], b, acc[fr][fc], 0, 0, 0);
        }
    }
    // store: D col = lane&15, row = (lane>>4)*4 + q
#pragma unroll
    for (int fr = 0; fr < 2; fr++) {
#pragma unroll
        for (int fc = 0; fc < 4; fc++) {
            int C = wc * 64 + fc * 16 + lr;
#pragma unroll
            for (int q = 0; q < 4; q++) {
                int R = row0 + wr * 32 + fr * 16 + (lane >> 4) * 4 + q;
                if (R < NN) Y[(size_t)R * DH + C] = __float2half(acc[fr][fc][q]);
            }
        }
    }
}

// ---------- aggregation: 2 nodes per wave, 8B/lane gathers ----------
__global__ __launch_bounds__(256) void k_agg(const __half* __restrict__ HW, const int* __restrict__ rowptr,
                                             const int* __restrict__ col, const float* __restrict__ wgt,
                                             const float* __restrict__ dis, const float* __restrict__ bias,
                                             float* __restrict__ OUT, float* __restrict__ ssum,
                                             float* __restrict__ ssq) {
    __shared__ float lsum[DH], lsq[DH];
    int t = threadIdx.x;
    if (t < DH) { lsum[t] = 0.f; lsq[t] = 0.f; }
    __syncthreads();
    int wid = t >> 6, lane = t & 63;
    int sub = lane >> 5, sl = lane & 31;
    const int2* HW4 = (const int2*)HW;
    float4* OUT4 = (float4*)OUT;
    float4 bv = ((const float4*)bias)[sl];
    float s0 = 0, s1 = 0, s2 = 0, s3 = 0, q0 = 0, q1 = 0, q2 = 0, q3 = 0;
    int gw = blockIdx.x * 4 + wid;
    for (int i = gw * 2 + sub; i < NN; i += 16384) {
        float sd = dis[i];
        int2 hr = HW4[i * 32 + sl];
        float2 f0 = __half22float2(*(__half2*)&hr.x);
        float2 f1 = __half22float2(*(__half2*)&hr.y);
        float a0 = sd * sd * f0.x, a1 = sd * sd * f0.y;
        float a2 = sd * sd * f1.x, a3 = sd * sd * f1.y;
        int p = rowptr[i], p1 = rowptr[i + 1];
        for (; p + 4 <= p1; p += 4) {
            int c0 = col[p], c1 = col[p + 1], c2 = col[p + 2], c3 = col[p + 3];
            float w0 = wgt[p], w1 = wgt[p + 1], w2 = wgt[p + 2], w3 = wgt[p + 3];
            int2 r0 = HW4[c0 * 32 + sl];
            int2 r1 = HW4[c1 * 32 + sl];
            int2 r2 = HW4[c2 * 32 + sl];
            int2 r3 = HW4[c3 * 32 + sl];
            float2 g0 = __half22float2(*(__half2*)&r0.x), g1 = __half22float2(*(__half2*)&r0.y);
            a0 = fmaf(w0, g0.x, a0); a1 = fmaf(w0, g0.y, a1); a2 = fmaf(w0, g1.x, a2); a3 = fmaf(w0, g1.y, a3);
            g0 = __half22float2(*(__half2*)&r1.x); g1 = __half22float2(*(__half2*)&r1.y);
            a0 = fmaf(w1, g0.x, a0); a1 = fmaf(w1, g0.y, a1); a2 = fmaf(w1, g1.x, a2); a3 = fmaf(w1, g1.y, a3);
            g0 = __half22float2(*(__half2*)&r2.x); g1 = __half22float2(*(__half2*)&r2.y);
            a0 = fmaf(w2, g0.x, a0); a1 = fmaf(w2, g0.y, a1); a2 = fmaf(w2, g1.x, a2); a3 = fmaf(w2, g1.y, a3);
            g0 = __half22float2(*(__half2*)&r3.x); g1 = __half22float2(*(__half2*)&r3.y);
            a0 = fmaf(w3, g0.x, a0); a1 = fmaf(w3, g0.y, a1); a2 = fmaf(w3, g1.x, a2); a3 = fmaf(w3, g1.y, a3);
        }
        for (; p < p1; p++) {
            int c = col[p];
            float wv = wgt[p];
            int2 r = HW4[c * 32 + sl];
            float2 g0 = __half22float2(*(__half2*)&r.x), g1 = __half22float2(*(__half2*)&r.y);
            a0 = fmaf(wv, g0.x, a0); a1 = fmaf(wv, g0.y, a1);
            a2 = fmaf(wv, g1.x, a2); a3 = fmaf(wv, g1.y, a3);
        }
        a0 += bv.x; a1 += bv.y; a2 += bv.z; a3 += bv.w;
        OUT4[i * 32 + sl] = make_float4(a0, a1, a2, a3);
        s0 += a0; s1 += a1; s2 += a2; s3 += a3;
        q0 += a0 * a0; q1 += a1 * a1; q2 += a2 * a2; q3 += a3 * a3;
    }
    atomicAdd(&lsum[sl * 4 + 0], s0); atomicAdd(&lsum[sl * 4 + 1], s1);
    atomicAdd(&lsum[sl * 4 + 2], s2); atomicAdd(&lsum[sl * 4 + 3], s3);
    atomicAdd(&lsq[sl * 4 + 0], q0);  atomicAdd(&lsq[sl * 4 + 1], q1);
    atomicAdd(&lsq[sl * 4 + 2], q2);  atomicAdd(&lsq[sl * 4 + 3], q3);
    __syncthreads();
    if (t < DH) { atomicAdd(&ssum[t], lsum[t]); atomicAdd(&ssq[t], lsq[t]); }
}

__global__ void k_bnfin(float* __restrict__ ssum, float* __restrict__ ssq,
                        const float* __restrict__ g, const float* __restrict__ be,
                        float* __restrict__ scale, float* __restrict__ shift) {
    int f = threadIdx.x;
    float m = ssum[f] * (1.f / NN);
    float v = ssq[f] * (1.f / NN) - m * m;
    float r = rsqrtf(v + BNEPS);
    float sc = r * g[f];
    scale[f] = sc;
    shift[f] = fmaf(-m, sc, be[f]);
    ssum[f] = 0.f;   // self-clean for next layer / next replay
    ssq[f] = 0.f;
}

// ---------- gate MLP (BN+ReLU of layer-4 fused into row load) ----------
__global__ __launch_bounds__(256) void k_gate(const float* __restrict__ H, const float* __restrict__ scale,
                                              const float* __restrict__ shift, const float* __restrict__ gw1,
                                              const float* __restrict__ gb1, const float* __restrict__ gw2,
                                              const float* __restrict__ gb2, float* __restrict__ gate) {
    __shared__ float w1s[DH * 64];
    __shared__ float rowbuf[4][DH];
    int t = threadIdx.x;
    for (int i = t; i < DH * 64; i += 256) w1s[i] = gw1[i];
    __syncthreads();
    int wid = t >> 6, lane = t & 63;
    float b1v = gb1[lane], w2v = gw2[lane], b2v = gb2[0];
    float2 sc2 = ((const float2*)scale)[lane];
    float2 sh2 = ((const float2*)shift)[lane];
    int nw = gridDim.x * 4;
    int iters = (NN + nw - 1) / nw;
    const float2* H2 = (const float2*)H;
    for (int it = 0; it < iters; it++) {
        int i = blockIdx.x * 4 + wid + it * nw;
        bool act = i < NN;
        if (act) {
            float2 hv = H2[i * 64 + lane];
            rowbuf[wid][lane * 2] = fmaxf(fmaf(hv.x, sc2.x, sh2.x), 0.f);
            rowbuf[wid][lane * 2 + 1] = fmaxf(fmaf(hv.y, sc2.y, sh2.y), 0.f);
        }
        __syncthreads();
        float hid = 0.f;
#pragma unroll 8
        for (int k = 0; k < DH; k++) hid = fmaf(rowbuf[wid][k], w1s[k * 64 + lane], hid);
        hid = fmaxf(hid + b1v, 0.f);
        float v = hid * w2v;
        for (int off = 32; off > 0; off >>= 1) v += __shfl_down(v, off, 64);
        if (act && lane == 0) gate[i] = v + b2v;
        __syncthreads();
    }
}

// ---------- per-group softmax stats (also zeroes pooled row) ----------
__device__ __forceinline__ int lbound(const int* __restrict__ a, int v) {
    int lo = 0, hi = NN;
    while (lo < hi) {
        int mid = (lo + hi) >> 1;
        if (a[mid] < v) lo = mid + 1; else hi = mid;
    }
    return lo;
}

__global__ __launch_bounds__(256) void k_pms(const float* __restrict__ gate, const int* __restrict__ batch,
                                             float* __restrict__ ms, float* __restrict__ pooled) {
    __shared__ float red[256];
    int g = blockIdx.x, t = threadIdx.x;
    if (t < DH) pooled[g * DH + t] = 0.f;
    int s = lbound(batch, g), e = lbound(batch, g + 1);
    float m = -INFINITY;
    for (int i = s + t; i < e; i += 256) m = fmaxf(m, gate[i]);
    red[t] = m; __syncthreads();
    for (int off = 128; off > 0; off >>= 1) { if (t < off) red[t] = fmaxf(red[t], red[t + off]); __syncthreads(); }
    m = red[0];
    __syncthreads();
    float se = 0.f;
    for (int i = s + t; i < e; i += 256) se += __expf(gate[i] - m);
    red[t] = se; __syncthreads();
    for (int off = 128; off > 0; off >>= 1) { if (t < off) red[t] += red[t + off]; __syncthreads(); }
    if (t == 0) {
        ms[g * 2] = m;
        ms[g * 2 + 1] = (e > s) ? 1.f / red[0] : 0.f;
    }
}

// ---------- node-parallel weighted pooling (BN+ReLU fused) ----------
#define PNODES 8
__global__ __launch_bounds__(256) void k_pool2(const float* __restrict__ H, const float* __restrict__ scale,
                                               const float* __restrict__ shift, const float* __restrict__ gate,
                                               const int* __restrict__ batch, const float* __restrict__ ms,
                                               float* __restrict__ pooled) {
    int wid = threadIdx.x >> 6, lane = threadIdx.x & 63;
    int base = (blockIdx.x * 4 + wid) * PNODES;
    if (base >= NN) return;
    int end = min(base + PNODES, NN);
    const float2* H2 = (const float2*)H;
    float2 sc2 = ((const float2*)scale)[lane];
    float2 sh2 = ((const float2*)shift)[lane];
    float2 acc = make_float2(0.f, 0.f);
    int curg = batch[base];
    for (int i = base; i < end; i++) {
        int g = batch[i];
        if (g != curg) {
            atomicAdd(&pooled[curg * DH + lane * 2], acc.x);
            atomicAdd(&pooled[curg * DH + lane * 2 + 1], acc.y);
            acc = make_float2(0.f, 0.f);
            curg = g;
        }
        float a = __expf(gate[i] - ms[g * 2]) * ms[g * 2 + 1];
        float2 h = H2[i * 64 + lane];
        float hx = fmaxf(fmaf(h.x, sc2.x, sh2.x), 0.f);
        float hy = fmaxf(fmaf(h.y, sc2.y, sh2.y), 0.f);
        acc.x = fmaf(a, hx, acc.x);
        acc.y = fmaf(a, hy, acc.y);
    }
    atomicAdd(&pooled[curg * DH + lane * 2], acc.x);
    atomicAdd(&pooled[curg * DH + lane * 2 + 1], acc.y);
}

// ---------- classifier ----------
__global__ __launch_bounds__(256) void k_cls(const float* __restrict__ pooled, const float* __restrict__ cw,
                                             const float* __restrict__ cb, float* __restrict__ out) {
    __shared__ float pr[DH];
    int g = blockIdx.y;
    if (threadIdx.x < DH) pr[threadIdx.x] = pooled[g * DH + threadIdx.x];
    __syncthreads();
    int j = blockIdx.x * 256 + threadIdx.x;
    if (j >= DOUT) return;
    float acc = cb[j];
#pragma unroll 8
    for (int k = 0; k < DH; k++) acc = fmaf(pr[k], cw[k * DOUT + j], acc);
    out[g * DOUT + j] = acc;
}

extern "C" void kernel_launch(void* const* d_in, const int* in_sizes, int n_in,
                              void* d_out, int out_size, void* d_ws, size_t ws_size,
                              hipStream_t stream) {
    const float* x     = (const float*)d_in[0];
    const int*   ei    = (const int*)d_in[1];
    const int*   batch = (const int*)d_in[2];
    const float* w[4]  = {(const float*)d_in[3], (const float*)d_in[7], (const float*)d_in[11], (const float*)d_in[15]};
    const float* bb[4] = {(const float*)d_in[4], (const float*)d_in[8], (const float*)d_in[12], (const float*)d_in[16]};
    const float* gg[4] = {(const float*)d_in[5], (const float*)d_in[9], (const float*)d_in[13], (const float*)d_in[17]};
    const float* be[4] = {(const float*)d_in[6], (const float*)d_in[10], (const float*)d_in[14], (const float*)d_in[18]};
    const float* gw1 = (const float*)d_in[19];
    const float* gb1 = (const float*)d_in[20];
    const float* gw2 = (const float*)d_in[21];
    const float* gb2 = (const float*)d_in[22];
    const float* cw  = (const float*)d_in[23];
    const float* cb  = (const float*)d_in[24];

    char* base = (char*)d_ws;
    size_t off = 0;
    auto take = [&](size_t n) -> char* { char* r = base + off; off = (off + n + 255) & ~(size_t)255; return r; };
    float*  bufA   = (float*)take((size_t)NN * DH * 4);
    __half* bufB   = (__half*)take((size_t)NN * DH * 2);
    int*   colv   = (int*)take((size_t)NE * 4);
    float* wgt    = (float*)take((size_t)NE * 4);
    int*   rowptr = (int*)take((size_t)(NN + 1) * 4);
    int*   cnt    = (int*)take((size_t)NN * 4);
    float* dis    = (float*)take((size_t)NN * 4);
    float* gate   = (float*)take((size_t)NN * 4);
    float* stats  = (float*)take(2 * DH * 4);
    float* ssum = stats, *ssq = stats + DH;
    float* scale  = (float*)take(DH * 4);
    float* shift  = (float*)take(DH * 4);
    float* pooled = (float*)take((size_t)NG * DH * 4);
    int*   bsum   = (int*)take((size_t)256 * 4);
    int*   boff   = (int*)take((size_t)256 * 4);
    float* ms     = (float*)take((size_t)NG * 2 * 4);
    __half* Wt    = (__half*)take((size_t)4 * DH * DH * 2);

    hipMemsetAsync(cnt, 0, NN * 4, stream);
    hipMemsetAsync(stats, 0, 2 * DH * 4, stream);
    k_count<<<(NE + 255) / 256, 256, 0, stream>>>(ei + NE, cnt);
    k_blkscan<<<NBLK, 256, 0, stream>>>(cnt, rowptr, bsum);
    k_bscan<<<1, 256, 0, stream>>>(bsum, boff);
    k_fin<<<NBLK, 256, 0, stream>>>(rowptr, boff, cnt, dis);
    k_fill<<<(NE + 255) / 256, 256, 0, stream>>>(ei, rowptr, cnt, dis, colv, wgt);
    k_wprep<<<64, 256, 0, stream>>>(w[0], w[1], w[2], w[3], Wt);

    const int gemm_grid = (NN + 63) / 64;
    for (int L = 0; L < 4; L++) {
        k_gemm3<<<gemm_grid, 256, 0, stream>>>(L == 0 ? x : bufA, Wt + (size_t)L * DH * DH,
                                               L == 0 ? nullptr : scale,
                                               L == 0 ? nullptr : shift, bufB);
        k_agg<<<2048, 256, 0, stream>>>(bufB, rowptr, colv, wgt, dis, bb[L], bufA, ssum, ssq);
        k_bnfin<<<1, DH, 0, stream>>>(ssum, ssq, gg[L], be[L], scale, shift);
    }
    k_gate<<<1024, 256, 0, stream>>>(bufA, scale, shift, gw1, gb1, gw2, gb2, gate);
    k_pms<<<NG, 256, 0, stream>>>(gate, batch, ms, pooled);
    k_pool2<<<(NN + 4 * PNODES - 1) / (4 * PNODES), 256, 0, stream>>>(bufA, scale, shift, gate, batch, ms, pooled);
    k_cls<<<dim3((DOUT + 255) / 256, NG), 256, 0, stream>>>(pooled, cw, cb, (float*)d_out);
}